// Round 3
// baseline (492.157 us; speedup 1.0000x reference)
//
#include <hip/hip_runtime.h>
#include <hip/hip_bf16.h>
#include <math.h>

#define NQ 9
#define NL 10
#define DIM 512
#define NCLS 10
#define B_TOT 16384

// ---------------------------------------------------------------------------
// One wave (64 lanes) simulates one 512-amp state entirely in registers.
// Amplitude index = lane*8 + r.  idx bits 0..2 = register r, bits 3..8 = lane.
// Qubit q <-> idx bit (8-q)  (qubit 0 is MSB after reshape(B,2,...,2)).
//   q=0..5  -> lane bit (5-q)  -> shfl_xor mask 32>>q
//   q=6,7,8 -> register stride 4,2,1
// Inputs: dtype (f32 vs bf16) detected at runtime per buffer (round-1 NaN
// proved at least some inputs are f32; detection keeps us robust either way).
// Output: float32 (reference returns f32; round-2 bf16 stores left half the
// f32 buffer zeroed -> absmax ~= zero-output baseline).
// ---------------------------------------------------------------------------

__device__ __forceinline__ float shx(float v, int m) { return __shfl_xor(v, m, 64); }

__device__ __forceinline__ int looks_bf16(const void* p, int count) {
  const unsigned short* u = (const unsigned short*)p;
  int n = count < 64 ? count : 64;
  int good = 0;
  for (int i = 0; i < n; ++i) {
    unsigned short v = u[i];
    int e = (v >> 7) & 0xFF;
    good += (e >= 100 && e <= 140) || ((v & 0x7FFF) == 0);
  }
  return good * 8 >= n * 7;
}

__device__ __forceinline__ float ld(const void* p, int i, int isbf) {
  if (isbf) return __uint_as_float(((unsigned)((const unsigned short*)p)[i]) << 16);
  return ((const float*)p)[i];
}

// Rot gate, target on a lane bit (mask M). u = 8 floats: U00,U01,U10,U11 (re,im)
template<int M>
__device__ __forceinline__ void rot_x(float (&sr)[8], float (&si)[8], const float* u) {
  float4 uA = *(const float4*)u;        // u00r,u00i,u01r,u01i
  float4 uB = *(const float4*)(u + 4);  // u10r,u10i,u11r,u11i
  bool hi = (threadIdx.x & M) != 0;
  float ar = hi ? uB.z : uA.x, ai = hi ? uB.w : uA.y;  // coeff on own amp
  float br = hi ? uB.x : uA.z, bi = hi ? uB.y : uA.w;  // coeff on partner amp
#pragma unroll
  for (int r = 0; r < 8; ++r) {
    float pr = shx(sr[r], M), pi = shx(si[r], M);
    float nr = ar * sr[r] - ai * si[r] + br * pr - bi * pi;
    float ni = ar * si[r] + ai * sr[r] + br * pi + bi * pr;
    sr[r] = nr; si[r] = ni;
  }
}

// Rot gate, target on a register bit (stride S in {1,2,4})
template<int S>
__device__ __forceinline__ void rot_r(float (&sr)[8], float (&si)[8], const float* u) {
  float4 uA = *(const float4*)u;
  float4 uB = *(const float4*)(u + 4);
#pragma unroll
  for (int r0 = 0; r0 < 8; ++r0) {
    if (r0 & S) continue;
    int r1 = r0 + S;
    float a0r = sr[r0], a0i = si[r0], a1r = sr[r1], a1i = si[r1];
    sr[r0] = uA.x * a0r - uA.y * a0i + uA.z * a1r - uA.w * a1i;
    si[r0] = uA.x * a0i + uA.y * a0r + uA.z * a1i + uA.w * a1r;
    sr[r1] = uB.x * a0r - uB.y * a0i + uB.z * a1r - uB.w * a1i;
    si[r1] = uB.x * a0i + uB.y * a0r + uB.z * a1i + uB.w * a1r;
  }
}

// CRX: new = c*own - i*s*partner where control bit = 1 (identity elsewhere).
template<int MC, int MT>
__device__ __forceinline__ void crx_ll(float (&sr)[8], float (&si)[8], const float* cs) {
  bool ctrl = (threadIdx.x & MC) != 0;
  float c = ctrl ? cs[0] : 1.0f;
  float s = ctrl ? cs[1] : 0.0f;
#pragma unroll
  for (int r = 0; r < 8; ++r) {
    float pr = shx(sr[r], MT), pi = shx(si[r], MT);
    float nr = c * sr[r] + s * pi;
    float ni = c * si[r] - s * pr;
    sr[r] = nr; si[r] = ni;
  }
}

template<int MC, int ST>
__device__ __forceinline__ void crx_lr(float (&sr)[8], float (&si)[8], const float* cs) {
  bool ctrl = (threadIdx.x & MC) != 0;
  float c = ctrl ? cs[0] : 1.0f;
  float s = ctrl ? cs[1] : 0.0f;
#pragma unroll
  for (int r0 = 0; r0 < 8; ++r0) {
    if (r0 & ST) continue;
    int r1 = r0 + ST;
    float a0r = sr[r0], a0i = si[r0], a1r = sr[r1], a1i = si[r1];
    sr[r0] = c * a0r + s * a1i;  si[r0] = c * a0i - s * a1r;
    sr[r1] = c * a1r + s * a0i;  si[r1] = c * a1i - s * a0r;
  }
}

template<int PC, int ST>
__device__ __forceinline__ void crx_rr(float (&sr)[8], float (&si)[8], const float* cs) {
  float c = cs[0], s = cs[1];
#pragma unroll
  for (int r0 = 0; r0 < 8; ++r0) {
    if (r0 & ST) continue;
    if (!((r0 >> PC) & 1)) continue;
    int r1 = r0 + ST;
    float a0r = sr[r0], a0i = si[r0], a1r = sr[r1], a1i = si[r1];
    sr[r0] = c * a0r + s * a1i;  si[r0] = c * a0i - s * a1r;
    sr[r1] = c * a1r + s * a0i;  si[r1] = c * a1i - s * a0r;
  }
}

template<int PC, int MT>
__device__ __forceinline__ void crx_rl(float (&sr)[8], float (&si)[8], const float* cs) {
  float c = cs[0], s = cs[1];
#pragma unroll
  for (int r = 0; r < 8; ++r) {
    if (!((r >> PC) & 1)) continue;
    float pr = shx(sr[r], MT), pi = shx(si[r], MT);
    float nr = c * sr[r] + s * pi;
    float ni = c * si[r] - s * pr;
    sr[r] = nr; si[r] = ni;
  }
}

__global__ __launch_bounds__(256) void qnn_kernel(
    const void* __restrict__ x,
    const void* __restrict__ rot,
    const void* __restrict__ crx,
    const void* __restrict__ fcw,
    const void* __restrict__ fcb,
    float* __restrict__ out) {
  __shared__ __align__(16) float gU[NL * NQ * 8];   // Rot 2x2 complex
  __shared__ __align__(16) float gCS[NL * NQ * 2];  // CRX cos,sin
  __shared__ int flags[5];                          // dtype per input buffer
  int tid = threadIdx.x;

  if (tid == 0) {
    flags[0] = looks_bf16(x, B_TOT * DIM);
    flags[1] = looks_bf16(rot, NL * NQ * 3);
    flags[2] = looks_bf16(crx, NL * NQ);
    flags[3] = looks_bf16(fcw, NCLS * NQ);
    flags[4] = looks_bf16(fcb, NCLS);
  }
  __syncthreads();

  if (tid < NL * NQ) {
    int frot = flags[1], fcrx = flags[2];
    float phi = ld(rot, tid * 3 + 0, frot);
    float th  = ld(rot, tid * 3 + 1, frot);
    float om  = ld(rot, tid * 3 + 2, frot);
    float c = cosf(0.5f * th), s = sinf(0.5f * th);
    float a = 0.5f * (phi + om), b = 0.5f * (phi - om);
    float ca = cosf(a), sa = sinf(a), cb = cosf(b), sb = sinf(b);
    float* u = gU + tid * 8;
    u[0] =  ca * c; u[1] = -sa * c;   // U00 = e^{-ia} c
    u[2] = -cb * s; u[3] = -sb * s;   // U01 = -e^{ib} s
    u[4] =  cb * s; u[5] = -sb * s;   // U10 = e^{-ib} s
    u[6] =  ca * c; u[7] =  sa * c;   // U11 = e^{ia} c
    float t2 = 0.5f * ld(crx, tid, fcrx);
    gCS[tid * 2 + 0] = cosf(t2);
    gCS[tid * 2 + 1] = sinf(t2);
  }
  __syncthreads();  // everything below is wave-synchronous

  int wid = (blockIdx.x * blockDim.x + tid) >> 6;  // state index
  int lane = tid & 63;

  // Load 8 amplitudes per lane (coalesced) and normalize
  float sr[8], si[8];
  if (flags[0]) {
    const ushort4 w = *(const ushort4*)((const unsigned short*)x + (size_t)wid * DIM + lane * 8);
    unsigned short v[4] = {w.x, w.y, w.z, w.w};
#pragma unroll
    for (int j = 0; j < 4; ++j) {
      sr[2 * j + 0] = __uint_as_float(((unsigned)v[j]) << 16);
      sr[2 * j + 1] = 0.f;  // placeholder, fixed below
    }
    // ushort4 is only 4 elems; reload properly as uint4 (8 bf16)
    const uint4 u = *(const uint4*)((const unsigned short*)x + (size_t)wid * DIM + lane * 8);
    sr[0] = __uint_as_float(u.x << 16); sr[1] = __uint_as_float(u.x & 0xffff0000u);
    sr[2] = __uint_as_float(u.y << 16); sr[3] = __uint_as_float(u.y & 0xffff0000u);
    sr[4] = __uint_as_float(u.z << 16); sr[5] = __uint_as_float(u.z & 0xffff0000u);
    sr[6] = __uint_as_float(u.w << 16); sr[7] = __uint_as_float(u.w & 0xffff0000u);
  } else {
    const float4* xf = (const float4*)((const float*)x + (size_t)wid * DIM) + lane * 2;
    float4 a = xf[0], b = xf[1];
    sr[0] = a.x; sr[1] = a.y; sr[2] = a.z; sr[3] = a.w;
    sr[4] = b.x; sr[5] = b.y; sr[6] = b.z; sr[7] = b.w;
  }
  float nrm = 0.f;
#pragma unroll
  for (int r = 0; r < 8; ++r) { nrm += sr[r] * sr[r]; si[r] = 0.f; }
#pragma unroll
  for (int m = 1; m < 64; m <<= 1) nrm += shx(nrm, m);
  float inv = rsqrtf(nrm);
  inv = inv * (1.5f - 0.5f * nrm * inv * inv);  // one Newton step
#pragma unroll
  for (int r = 0; r < 8; ++r) sr[r] *= inv;

#pragma unroll 1
  for (int n = 0; n < NL; ++n) {
    const float* U  = gU  + n * NQ * 8;
    const float* CS = gCS + n * NQ * 2;
    // 9 Rot gates, qubits 0..8
    rot_x<32>(sr, si, U + 0 * 8);
    rot_x<16>(sr, si, U + 1 * 8);
    rot_x< 8>(sr, si, U + 2 * 8);
    rot_x< 4>(sr, si, U + 3 * 8);
    rot_x< 2>(sr, si, U + 4 * 8);
    rot_x< 1>(sr, si, U + 5 * 8);
    rot_r< 4>(sr, si, U + 6 * 8);
    rot_r< 2>(sr, si, U + 7 * 8);
    rot_r< 1>(sr, si, U + 8 * 8);
    // 9 CRX gates, control c -> target (c+1)%9, applied in order
    crx_ll<32, 16>(sr, si, CS + 0 * 2);
    crx_ll<16,  8>(sr, si, CS + 1 * 2);
    crx_ll< 8,  4>(sr, si, CS + 2 * 2);
    crx_ll< 4,  2>(sr, si, CS + 3 * 2);
    crx_ll< 2,  1>(sr, si, CS + 4 * 2);
    crx_lr< 1,  4>(sr, si, CS + 5 * 2);
    crx_rr< 2,  2>(sr, si, CS + 6 * 2);
    crx_rr< 1,  1>(sr, si, CS + 7 * 2);
    crx_rl< 0, 32>(sr, si, CS + 8 * 2);
  }

  // probabilities and <Z_q>
  float p[8], P = 0.f;
#pragma unroll
  for (int r = 0; r < 8; ++r) { p[r] = sr[r] * sr[r] + si[r] * si[r]; P += p[r]; }
  float z[NQ];
#pragma unroll
  for (int q = 0; q < 6; ++q) z[q] = (lane & (32 >> q)) ? -P : P;
  z[6] = z[7] = z[8] = 0.f;
#pragma unroll
  for (int r = 0; r < 8; ++r) {
    z[6] += (r & 4) ? -p[r] : p[r];
    z[7] += (r & 2) ? -p[r] : p[r];
    z[8] += (r & 1) ? -p[r] : p[r];
  }
#pragma unroll
  for (int m = 1; m < 64; m <<= 1) {
#pragma unroll
    for (int q = 0; q < NQ; ++q) z[q] += shx(z[q], m);
  }

  // logits + log_softmax (redundant per lane; lanes 0..9 store)
  int ffw = flags[3], ffb = flags[4];
  float lg[NCLS], mx = -1e30f;
#pragma unroll
  for (int k = 0; k < NCLS; ++k) {
    float t = ld(fcb, k, ffb);
#pragma unroll
    for (int q = 0; q < NQ; ++q) t += z[q] * ld(fcw, k * NQ + q, ffw);
    lg[k] = t; mx = fmaxf(mx, t);
  }
  float se = 0.f;
#pragma unroll
  for (int k = 0; k < NCLS; ++k) se += expf(lg[k] - mx);
  float lse = mx + logf(se);
  if (lane < NCLS) out[(size_t)wid * NCLS + lane] = lg[lane] - lse;  // f32 store
}

extern "C" void kernel_launch(void* const* d_in, const int* in_sizes, int n_in,
                              void* d_out, int out_size, void* d_ws, size_t ws_size,
                              hipStream_t stream) {
  // 16384 states, 1 wave each, 4 waves per block -> 4096 blocks
  int nblocks = (B_TOT * 64) / 256;
  qnn_kernel<<<nblocks, 256, 0, stream>>>(d_in[0], d_in[1], d_in[2], d_in[3], d_in[4],
                                          (float*)d_out);
}

// Round 4
// 206.767 us; speedup vs baseline: 2.3802x; 2.3802x over previous
//
#include <hip/hip_runtime.h>
#include <hip/hip_bf16.h>
#include <math.h>

#define NQ 9
#define NL 10
#define DIM 512
#define NCLS 10
#define B_TOT 16384

// ws layout (bytes): A bf16 [16384x512] @ 0 (16MB); BT bf16 [1024x512] @ 16MB (1MB);
// C f32 [16384x1024] @ 32MB (64MB).  Need 96MB; else fall back to mono kernel.
#define A_OFF   ((size_t)0)
#define BT_OFF  ((size_t)16 << 20)
#define C_OFF   ((size_t)32 << 20)
#define WS_NEED (((size_t)96) << 20)

__device__ __forceinline__ float shx(float v, int m) { return __shfl_xor(v, m, 64); }

__device__ __forceinline__ int looks_bf16(const void* p, int count) {
  const unsigned short* u = (const unsigned short*)p;
  int n = count < 64 ? count : 64;
  int good = 0;
  for (int i = 0; i < n; ++i) {
    unsigned short v = u[i];
    int e = (v >> 7) & 0xFF;
    good += (e >= 100 && e <= 140) || ((v & 0x7FFF) == 0);
  }
  return good * 8 >= n * 7;
}

__device__ __forceinline__ float ld(const void* p, int i, int isbf) {
  if (isbf) return __uint_as_float(((unsigned)((const unsigned short*)p)[i]) << 16);
  return ((const float*)p)[i];
}

// ---------------- verified gate helpers (round-3 code, unchanged) ----------
template<int M>
__device__ __forceinline__ void rot_x(float (&sr)[8], float (&si)[8], const float* u) {
  float4 uA = *(const float4*)u;
  float4 uB = *(const float4*)(u + 4);
  bool hi = (threadIdx.x & M) != 0;
  float ar = hi ? uB.z : uA.x, ai = hi ? uB.w : uA.y;
  float br = hi ? uB.x : uA.z, bi = hi ? uB.y : uA.w;
#pragma unroll
  for (int r = 0; r < 8; ++r) {
    float pr = shx(sr[r], M), pi = shx(si[r], M);
    float nr = ar * sr[r] - ai * si[r] + br * pr - bi * pi;
    float ni = ar * si[r] + ai * sr[r] + br * pi + bi * pr;
    sr[r] = nr; si[r] = ni;
  }
}
template<int S>
__device__ __forceinline__ void rot_r(float (&sr)[8], float (&si)[8], const float* u) {
  float4 uA = *(const float4*)u;
  float4 uB = *(const float4*)(u + 4);
#pragma unroll
  for (int r0 = 0; r0 < 8; ++r0) {
    if (r0 & S) continue;
    int r1 = r0 + S;
    float a0r = sr[r0], a0i = si[r0], a1r = sr[r1], a1i = si[r1];
    sr[r0] = uA.x * a0r - uA.y * a0i + uA.z * a1r - uA.w * a1i;
    si[r0] = uA.x * a0i + uA.y * a0r + uA.z * a1i + uA.w * a1r;
    sr[r1] = uB.x * a0r - uB.y * a0i + uB.z * a1r - uB.w * a1i;
    si[r1] = uB.x * a0i + uB.y * a0r + uB.z * a1i + uB.w * a1r;
  }
}
template<int MC, int MT>
__device__ __forceinline__ void crx_ll(float (&sr)[8], float (&si)[8], const float* cs) {
  bool ctrl = (threadIdx.x & MC) != 0;
  float c = ctrl ? cs[0] : 1.0f;
  float s = ctrl ? cs[1] : 0.0f;
#pragma unroll
  for (int r = 0; r < 8; ++r) {
    float pr = shx(sr[r], MT), pi = shx(si[r], MT);
    float nr = c * sr[r] + s * pi;
    float ni = c * si[r] - s * pr;
    sr[r] = nr; si[r] = ni;
  }
}
template<int MC, int ST>
__device__ __forceinline__ void crx_lr(float (&sr)[8], float (&si)[8], const float* cs) {
  bool ctrl = (threadIdx.x & MC) != 0;
  float c = ctrl ? cs[0] : 1.0f;
  float s = ctrl ? cs[1] : 0.0f;
#pragma unroll
  for (int r0 = 0; r0 < 8; ++r0) {
    if (r0 & ST) continue;
    int r1 = r0 + ST;
    float a0r = sr[r0], a0i = si[r0], a1r = sr[r1], a1i = si[r1];
    sr[r0] = c * a0r + s * a1i;  si[r0] = c * a0i - s * a1r;
    sr[r1] = c * a1r + s * a0i;  si[r1] = c * a1i - s * a0r;
  }
}
template<int PC, int ST>
__device__ __forceinline__ void crx_rr(float (&sr)[8], float (&si)[8], const float* cs) {
  float c = cs[0], s = cs[1];
#pragma unroll
  for (int r0 = 0; r0 < 8; ++r0) {
    if (r0 & ST) continue;
    if (!((r0 >> PC) & 1)) continue;
    int r1 = r0 + ST;
    float a0r = sr[r0], a0i = si[r0], a1r = sr[r1], a1i = si[r1];
    sr[r0] = c * a0r + s * a1i;  si[r0] = c * a0i - s * a1r;
    sr[r1] = c * a1r + s * a0i;  si[r1] = c * a1i - s * a0r;
  }
}
template<int PC, int MT>
__device__ __forceinline__ void crx_rl(float (&sr)[8], float (&si)[8], const float* cs) {
  float c = cs[0], s = cs[1];
#pragma unroll
  for (int r = 0; r < 8; ++r) {
    if (!((r >> PC) & 1)) continue;
    float pr = shx(sr[r], MT), pi = shx(si[r], MT);
    float nr = c * sr[r] + s * pi;
    float ni = c * si[r] - s * pr;
    sr[r] = nr; si[r] = ni;
  }
}

// gate-table build (per block, threads 0..89)
__device__ __forceinline__ void build_gates(const void* rot, const void* crx,
                                            float* gU, float* gCS) {
  int tid = threadIdx.x;
  __shared__ int gflags[2];
  if (tid == 0) {
    gflags[0] = looks_bf16(rot, NL * NQ * 3);
    gflags[1] = looks_bf16(crx, NL * NQ);
  }
  __syncthreads();
  if (tid < NL * NQ) {
    int frot = gflags[0], fcrx = gflags[1];
    float phi = ld(rot, tid * 3 + 0, frot);
    float th  = ld(rot, tid * 3 + 1, frot);
    float om  = ld(rot, tid * 3 + 2, frot);
    float c = cosf(0.5f * th), s = sinf(0.5f * th);
    float a = 0.5f * (phi + om), b = 0.5f * (phi - om);
    float ca = cosf(a), sa = sinf(a), cb = cosf(b), sb = sinf(b);
    float* u = gU + tid * 8;
    u[0] =  ca * c; u[1] = -sa * c;
    u[2] = -cb * s; u[3] = -sb * s;
    u[4] =  cb * s; u[5] = -sb * s;
    u[6] =  ca * c; u[7] =  sa * c;
    float t2 = 0.5f * ld(crx, tid, fcrx);
    gCS[tid * 2 + 0] = cosf(t2);
    gCS[tid * 2 + 1] = sinf(t2);
  }
  __syncthreads();
}

__device__ __forceinline__ void run_circuit(float (&sr)[8], float (&si)[8],
                                            const float* gU, const float* gCS) {
#pragma unroll 1
  for (int n = 0; n < NL; ++n) {
    const float* U  = gU  + n * NQ * 8;
    const float* CS = gCS + n * NQ * 2;
    rot_x<32>(sr, si, U + 0 * 8);
    rot_x<16>(sr, si, U + 1 * 8);
    rot_x< 8>(sr, si, U + 2 * 8);
    rot_x< 4>(sr, si, U + 3 * 8);
    rot_x< 2>(sr, si, U + 4 * 8);
    rot_x< 1>(sr, si, U + 5 * 8);
    rot_r< 4>(sr, si, U + 6 * 8);
    rot_r< 2>(sr, si, U + 7 * 8);
    rot_r< 1>(sr, si, U + 8 * 8);
    crx_ll<32, 16>(sr, si, CS + 0 * 2);
    crx_ll<16,  8>(sr, si, CS + 1 * 2);
    crx_ll< 8,  4>(sr, si, CS + 2 * 2);
    crx_ll< 4,  2>(sr, si, CS + 3 * 2);
    crx_ll< 2,  1>(sr, si, CS + 4 * 2);
    crx_lr< 1,  4>(sr, si, CS + 5 * 2);
    crx_rr< 2,  2>(sr, si, CS + 6 * 2);
    crx_rr< 1,  1>(sr, si, CS + 7 * 2);
    crx_rl< 0, 32>(sr, si, CS + 8 * 2);
  }
}

// ---------------- pipeline kernel 1: cast x -> bf16 A ----------------------
__global__ __launch_bounds__(256) void cast_kernel(const void* __restrict__ x,
                                                   __hip_bfloat16* __restrict__ A) {
  __shared__ int fx;
  if (threadIdx.x == 0) fx = looks_bf16(x, B_TOT * DIM);
  __syncthreads();
  size_t i0 = ((size_t)blockIdx.x * 256 + threadIdx.x) * 8;  // 8 elems/thread
  if (fx) {
    *(uint4*)(A + i0) = *(const uint4*)((const unsigned short*)x + i0);
  } else {
    const float4* src = (const float4*)((const float*)x + i0);
    float4 a = src[0], b = src[1];
    __hip_bfloat16 o[8];
    o[0] = __float2bfloat16(a.x); o[1] = __float2bfloat16(a.y);
    o[2] = __float2bfloat16(a.z); o[3] = __float2bfloat16(a.w);
    o[4] = __float2bfloat16(b.x); o[5] = __float2bfloat16(b.y);
    o[6] = __float2bfloat16(b.z); o[7] = __float2bfloat16(b.w);
    *(uint4*)(A + i0) = *(uint4*)o;
  }
}

// ------- pipeline kernel 2: build BT[n][k] = element (j,k) of [ReW; ImW] ---
// wave k simulates basis state e_k; lane/reg hold W[j,k] for j=lane*8+r.
__global__ __launch_bounds__(256) void wbuild_kernel(const void* __restrict__ rot,
                                                     const void* __restrict__ crx,
                                                     __hip_bfloat16* __restrict__ BT) {
  __shared__ __align__(16) float gU[NL * NQ * 8];
  __shared__ __align__(16) float gCS[NL * NQ * 2];
  build_gates(rot, crx, gU, gCS);
  int tid = threadIdx.x;
  int k = (blockIdx.x * 256 + tid) >> 6;  // basis index 0..511
  int lane = tid & 63;
  float sr[8], si[8];
#pragma unroll
  for (int r = 0; r < 8; ++r) {
    sr[r] = (lane * 8 + r == k) ? 1.0f : 0.0f;
    si[r] = 0.0f;
  }
  run_circuit(sr, si, gU, gCS);
#pragma unroll
  for (int r = 0; r < 8; ++r) {
    int j = lane * 8 + r;
    BT[(size_t)j * DIM + k]         = __float2bfloat16(sr[r]);  // Re W[j,k]
    BT[(size_t)(DIM + j) * DIM + k] = __float2bfloat16(si[r]);  // Im W[j,k]
  }
}

// ---------------- pipeline kernel 3: C = A x BT' (bf16 MFMA GEMM) ----------
// M=16384, N=1024, K=512.  128x128 tile, 4 waves 2x2, 16x16x32 bf16 MFMA.
using frag8 = __attribute__((ext_vector_type(8))) short;
using frag4 = __attribute__((ext_vector_type(4))) float;
#define LDP 40  // lds row pitch (bf16 elems): pads 32->40 to spread banks

__global__ __launch_bounds__(256) void gemm_kernel(const unsigned short* __restrict__ A,
                                                   const unsigned short* __restrict__ BT,
                                                   float* __restrict__ C) {
  __shared__ __align__(16) unsigned short lA[128 * LDP];
  __shared__ __align__(16) unsigned short lB[128 * LDP];
  int tid = threadIdx.x;
  int wid = tid >> 6, lane = tid & 63;
  int wm = wid >> 1, wn = wid & 1;
  int m0 = blockIdx.x * 128;
  int n0 = blockIdx.y * 128;
  int row = lane & 15, quad = lane >> 4;
  frag4 acc[4][4] = {};
#pragma unroll 1
  for (int k0 = 0; k0 < 512; k0 += 32) {
    __syncthreads();
#pragma unroll
    for (int s = tid; s < 512; s += 256) {  // 128 rows x 4 chunks of 16B
      int rr = s >> 2, cc = s & 3;
      *(uint4*)(&lA[rr * LDP + cc * 8]) =
          *(const uint4*)(&A[(size_t)(m0 + rr) * 512 + k0 + cc * 8]);
      *(uint4*)(&lB[rr * LDP + cc * 8]) =
          *(const uint4*)(&BT[(size_t)(n0 + rr) * 512 + k0 + cc * 8]);
    }
    __syncthreads();
    frag8 af[4], bf[4];
#pragma unroll
    for (int i = 0; i < 4; ++i) {
      af[i] = *(const frag8*)(&lA[(wm * 64 + i * 16 + row) * LDP + quad * 8]);
      bf[i] = *(const frag8*)(&lB[(wn * 64 + i * 16 + row) * LDP + quad * 8]);
    }
#pragma unroll
    for (int mi = 0; mi < 4; ++mi)
#pragma unroll
      for (int ni = 0; ni < 4; ++ni)
        acc[mi][ni] = __builtin_amdgcn_mfma_f32_16x16x32_bf16(af[mi], bf[ni],
                                                              acc[mi][ni], 0, 0, 0);
  }
  // C/D layout: col = lane&15, row = (lane>>4)*4 + reg   [m89/m91 verified]
#pragma unroll
  for (int mi = 0; mi < 4; ++mi)
#pragma unroll
    for (int ni = 0; ni < 4; ++ni)
#pragma unroll
      for (int rg = 0; rg < 4; ++rg) {
        int m = m0 + wm * 64 + mi * 16 + quad * 4 + rg;
        int n = n0 + wn * 64 + ni * 16 + row;
        C[(size_t)m * 1024 + n] = acc[mi][ni][rg];
      }
}

// ---------------- pipeline kernel 4: probs -> z -> logits -> log_softmax ---
__global__ __launch_bounds__(256) void epi_kernel(const float* __restrict__ C,
                                                  const void* __restrict__ fcw,
                                                  const void* __restrict__ fcb,
                                                  float* __restrict__ out) {
  __shared__ int flags[2];
  int tid = threadIdx.x;
  if (tid == 0) {
    flags[0] = looks_bf16(fcw, NCLS * NQ);
    flags[1] = looks_bf16(fcb, NCLS);
  }
  __syncthreads();
  int b = (blockIdx.x * 256 + tid) >> 6;
  int lane = tid & 63;
  const float* rowp = C + (size_t)b * 1024;
  const float4* pr4 = (const float4*)(rowp + lane * 8);
  const float4* pi4 = (const float4*)(rowp + 512 + lane * 8);
  float4 r0 = pr4[0], r1 = pr4[1], i0 = pi4[0], i1 = pi4[1];
  float cr[8] = {r0.x, r0.y, r0.z, r0.w, r1.x, r1.y, r1.z, r1.w};
  float ci[8] = {i0.x, i0.y, i0.z, i0.w, i1.x, i1.y, i1.z, i1.w};
  float p[8], P = 0.f;
#pragma unroll
  for (int r = 0; r < 8; ++r) { p[r] = cr[r] * cr[r] + ci[r] * ci[r]; P += p[r]; }
  float z[NQ + 1];
#pragma unroll
  for (int q = 0; q < 6; ++q) z[q] = (lane & (32 >> q)) ? -P : P;
  z[6] = z[7] = z[8] = 0.f;
#pragma unroll
  for (int r = 0; r < 8; ++r) {
    z[6] += (r & 4) ? -p[r] : p[r];
    z[7] += (r & 2) ? -p[r] : p[r];
    z[8] += (r & 1) ? -p[r] : p[r];
  }
  z[9] = P;  // total norm^2 (input was unnormalized; unitary preserves norm)
#pragma unroll
  for (int m = 1; m < 64; m <<= 1) {
#pragma unroll
    for (int q = 0; q < NQ + 1; ++q) z[q] += shx(z[q], m);
  }
  float invP = 1.0f / z[9];
#pragma unroll
  for (int q = 0; q < NQ; ++q) z[q] *= invP;
  int ffw = flags[0], ffb = flags[1];
  float lg[NCLS], mx = -1e30f;
#pragma unroll
  for (int k = 0; k < NCLS; ++k) {
    float t = ld(fcb, k, ffb);
#pragma unroll
    for (int q = 0; q < NQ; ++q) t += z[q] * ld(fcw, k * NQ + q, ffw);
    lg[k] = t; mx = fmaxf(mx, t);
  }
  float se = 0.f;
#pragma unroll
  for (int k = 0; k < NCLS; ++k) se += expf(lg[k] - mx);
  float lse = mx + logf(se);
  if (lane < NCLS) out[(size_t)b * NCLS + lane] = lg[lane] - lse;
}

// ---------------- fallback: round-3 passing monolithic kernel --------------
__global__ __launch_bounds__(256) void qnn_kernel(
    const void* __restrict__ x, const void* __restrict__ rot,
    const void* __restrict__ crx, const void* __restrict__ fcw,
    const void* __restrict__ fcb, float* __restrict__ out) {
  __shared__ __align__(16) float gU[NL * NQ * 8];
  __shared__ __align__(16) float gCS[NL * NQ * 2];
  __shared__ int flags[3];
  int tid = threadIdx.x;
  if (tid == 0) {
    flags[0] = looks_bf16(x, B_TOT * DIM);
    flags[1] = looks_bf16(fcw, NCLS * NQ);
    flags[2] = looks_bf16(fcb, NCLS);
  }
  build_gates(rot, crx, gU, gCS);
  __syncthreads();
  int wid = (blockIdx.x * blockDim.x + tid) >> 6;
  int lane = tid & 63;
  float sr[8], si[8];
  if (flags[0]) {
    const uint4 u = *(const uint4*)((const unsigned short*)x + (size_t)wid * DIM + lane * 8);
    sr[0] = __uint_as_float(u.x << 16); sr[1] = __uint_as_float(u.x & 0xffff0000u);
    sr[2] = __uint_as_float(u.y << 16); sr[3] = __uint_as_float(u.y & 0xffff0000u);
    sr[4] = __uint_as_float(u.z << 16); sr[5] = __uint_as_float(u.z & 0xffff0000u);
    sr[6] = __uint_as_float(u.w << 16); sr[7] = __uint_as_float(u.w & 0xffff0000u);
  } else {
    const float4* xf = (const float4*)((const float*)x + (size_t)wid * DIM) + lane * 2;
    float4 a = xf[0], b = xf[1];
    sr[0] = a.x; sr[1] = a.y; sr[2] = a.z; sr[3] = a.w;
    sr[4] = b.x; sr[5] = b.y; sr[6] = b.z; sr[7] = b.w;
  }
  float nrm = 0.f;
#pragma unroll
  for (int r = 0; r < 8; ++r) { nrm += sr[r] * sr[r]; si[r] = 0.f; }
#pragma unroll
  for (int m = 1; m < 64; m <<= 1) nrm += shx(nrm, m);
  float inv = rsqrtf(nrm);
  inv = inv * (1.5f - 0.5f * nrm * inv * inv);
#pragma unroll
  for (int r = 0; r < 8; ++r) sr[r] *= inv;
  run_circuit(sr, si, gU, gCS);
  float p[8], P = 0.f;
#pragma unroll
  for (int r = 0; r < 8; ++r) { p[r] = sr[r] * sr[r] + si[r] * si[r]; P += p[r]; }
  float z[NQ];
#pragma unroll
  for (int q = 0; q < 6; ++q) z[q] = (lane & (32 >> q)) ? -P : P;
  z[6] = z[7] = z[8] = 0.f;
#pragma unroll
  for (int r = 0; r < 8; ++r) {
    z[6] += (r & 4) ? -p[r] : p[r];
    z[7] += (r & 2) ? -p[r] : p[r];
    z[8] += (r & 1) ? -p[r] : p[r];
  }
#pragma unroll
  for (int m = 1; m < 64; m <<= 1) {
#pragma unroll
    for (int q = 0; q < NQ; ++q) z[q] += shx(z[q], m);
  }
  int ffw = flags[1], ffb = flags[2];
  float lg[NCLS], mx = -1e30f;
#pragma unroll
  for (int k = 0; k < NCLS; ++k) {
    float t = ld(fcb, k, ffb);
#pragma unroll
    for (int q = 0; q < NQ; ++q) t += z[q] * ld(fcw, k * NQ + q, ffw);
    lg[k] = t; mx = fmaxf(mx, t);
  }
  float se = 0.f;
#pragma unroll
  for (int k = 0; k < NCLS; ++k) se += expf(lg[k] - mx);
  float lse = mx + logf(se);
  if (lane < NCLS) out[(size_t)wid * NCLS + lane] = lg[lane] - lse;
}

extern "C" void kernel_launch(void* const* d_in, const int* in_sizes, int n_in,
                              void* d_out, int out_size, void* d_ws, size_t ws_size,
                              hipStream_t stream) {
  const void* x   = d_in[0];
  const void* rot = d_in[1];
  const void* crx = d_in[2];
  const void* fcw = d_in[3];
  const void* fcb = d_in[4];
  float* out = (float*)d_out;
  if (ws_size >= WS_NEED) {
    __hip_bfloat16* A  = (__hip_bfloat16*)((char*)d_ws + A_OFF);
    __hip_bfloat16* BT = (__hip_bfloat16*)((char*)d_ws + BT_OFF);
    float*          C  = (float*)((char*)d_ws + C_OFF);
    cast_kernel<<<(B_TOT * DIM) / (256 * 8), 256, 0, stream>>>(x, A);
    wbuild_kernel<<<(DIM * 64) / 256, 256, 0, stream>>>(rot, crx, BT);
    dim3 gg(B_TOT / 128, 1024 / 128);
    gemm_kernel<<<gg, 256, 0, stream>>>((const unsigned short*)A,
                                        (const unsigned short*)BT, C);
    epi_kernel<<<(B_TOT * 64) / 256, 256, 0, stream>>>(C, fcw, fcb, out);
  } else {
    qnn_kernel<<<(B_TOT * 64) / 256, 256, 0, stream>>>(x, rot, crx, fcw, fcb, out);
  }
}

// Round 5
// 194.533 us; speedup vs baseline: 2.5299x; 1.0629x over previous
//
#include <hip/hip_runtime.h>
#include <hip/hip_bf16.h>
#include <math.h>

#define NQ 9
#define NL 10
#define DIM 512
#define NCLS 10
#define B_TOT 16384

// ws layout (bytes): A bf16 [16384x512] @ 0 (16MB); BT bf16 [1024x512] @ 16MB (1MB);
// C f32 [16384x1024] @ 32MB (64MB).  Need 96MB; else fall back to mono kernel.
#define A_OFF   ((size_t)0)
#define BT_OFF  ((size_t)16 << 20)
#define C_OFF   ((size_t)32 << 20)
#define WS_NEED (((size_t)96) << 20)

__device__ __forceinline__ float shx(float v, int m) { return __shfl_xor(v, m, 64); }

__device__ __forceinline__ int looks_bf16(const void* p, int count) {
  const unsigned short* u = (const unsigned short*)p;
  int n = count < 64 ? count : 64;
  int good = 0;
  for (int i = 0; i < n; ++i) {
    unsigned short v = u[i];
    int e = (v >> 7) & 0xFF;
    good += (e >= 100 && e <= 140) || ((v & 0x7FFF) == 0);
  }
  return good * 8 >= n * 7;
}

__device__ __forceinline__ float ld(const void* p, int i, int isbf) {
  if (isbf) return __uint_as_float(((unsigned)((const unsigned short*)p)[i]) << 16);
  return ((const float*)p)[i];
}

// ---------------- verified gate helpers (round-3, unchanged) ---------------
template<int M>
__device__ __forceinline__ void rot_x(float (&sr)[8], float (&si)[8], const float* u) {
  float4 uA = *(const float4*)u;
  float4 uB = *(const float4*)(u + 4);
  bool hi = (threadIdx.x & M) != 0;
  float ar = hi ? uB.z : uA.x, ai = hi ? uB.w : uA.y;
  float br = hi ? uB.x : uA.z, bi = hi ? uB.y : uA.w;
#pragma unroll
  for (int r = 0; r < 8; ++r) {
    float pr = shx(sr[r], M), pi = shx(si[r], M);
    float nr = ar * sr[r] - ai * si[r] + br * pr - bi * pi;
    float ni = ar * si[r] + ai * sr[r] + br * pi + bi * pr;
    sr[r] = nr; si[r] = ni;
  }
}
template<int S>
__device__ __forceinline__ void rot_r(float (&sr)[8], float (&si)[8], const float* u) {
  float4 uA = *(const float4*)u;
  float4 uB = *(const float4*)(u + 4);
#pragma unroll
  for (int r0 = 0; r0 < 8; ++r0) {
    if (r0 & S) continue;
    int r1 = r0 + S;
    float a0r = sr[r0], a0i = si[r0], a1r = sr[r1], a1i = si[r1];
    sr[r0] = uA.x * a0r - uA.y * a0i + uA.z * a1r - uA.w * a1i;
    si[r0] = uA.x * a0i + uA.y * a0r + uA.z * a1i + uA.w * a1r;
    sr[r1] = uB.x * a0r - uB.y * a0i + uB.z * a1r - uB.w * a1i;
    si[r1] = uB.x * a0i + uB.y * a0r + uB.z * a1i + uB.w * a1r;
  }
}
template<int MC, int MT>
__device__ __forceinline__ void crx_ll(float (&sr)[8], float (&si)[8], const float* cs) {
  bool ctrl = (threadIdx.x & MC) != 0;
  float c = ctrl ? cs[0] : 1.0f;
  float s = ctrl ? cs[1] : 0.0f;
#pragma unroll
  for (int r = 0; r < 8; ++r) {
    float pr = shx(sr[r], MT), pi = shx(si[r], MT);
    float nr = c * sr[r] + s * pi;
    float ni = c * si[r] - s * pr;
    sr[r] = nr; si[r] = ni;
  }
}
template<int MC, int ST>
__device__ __forceinline__ void crx_lr(float (&sr)[8], float (&si)[8], const float* cs) {
  bool ctrl = (threadIdx.x & MC) != 0;
  float c = ctrl ? cs[0] : 1.0f;
  float s = ctrl ? cs[1] : 0.0f;
#pragma unroll
  for (int r0 = 0; r0 < 8; ++r0) {
    if (r0 & ST) continue;
    int r1 = r0 + ST;
    float a0r = sr[r0], a0i = si[r0], a1r = sr[r1], a1i = si[r1];
    sr[r0] = c * a0r + s * a1i;  si[r0] = c * a0i - s * a1r;
    sr[r1] = c * a1r + s * a0i;  si[r1] = c * a1i - s * a0r;
  }
}
template<int PC, int ST>
__device__ __forceinline__ void crx_rr(float (&sr)[8], float (&si)[8], const float* cs) {
  float c = cs[0], s = cs[1];
#pragma unroll
  for (int r0 = 0; r0 < 8; ++r0) {
    if (r0 & ST) continue;
    if (!((r0 >> PC) & 1)) continue;
    int r1 = r0 + ST;
    float a0r = sr[r0], a0i = si[r0], a1r = sr[r1], a1i = si[r1];
    sr[r0] = c * a0r + s * a1i;  si[r0] = c * a0i - s * a1r;
    sr[r1] = c * a1r + s * a0i;  si[r1] = c * a1i - s * a0r;
  }
}
template<int PC, int MT>
__device__ __forceinline__ void crx_rl(float (&sr)[8], float (&si)[8], const float* cs) {
  float c = cs[0], s = cs[1];
#pragma unroll
  for (int r = 0; r < 8; ++r) {
    if (!((r >> PC) & 1)) continue;
    float pr = shx(sr[r], MT), pi = shx(si[r], MT);
    float nr = c * sr[r] + s * pi;
    float ni = c * si[r] - s * pr;
    sr[r] = nr; si[r] = ni;
  }
}

__device__ __forceinline__ void build_gates(const void* rot, const void* crx,
                                            float* gU, float* gCS) {
  int tid = threadIdx.x;
  __shared__ int gflags[2];
  if (tid == 0) {
    gflags[0] = looks_bf16(rot, NL * NQ * 3);
    gflags[1] = looks_bf16(crx, NL * NQ);
  }
  __syncthreads();
  if (tid < NL * NQ) {
    int frot = gflags[0], fcrx = gflags[1];
    float phi = ld(rot, tid * 3 + 0, frot);
    float th  = ld(rot, tid * 3 + 1, frot);
    float om  = ld(rot, tid * 3 + 2, frot);
    float c = cosf(0.5f * th), s = sinf(0.5f * th);
    float a = 0.5f * (phi + om), b = 0.5f * (phi - om);
    float ca = cosf(a), sa = sinf(a), cb = cosf(b), sb = sinf(b);
    float* u = gU + tid * 8;
    u[0] =  ca * c; u[1] = -sa * c;
    u[2] = -cb * s; u[3] = -sb * s;
    u[4] =  cb * s; u[5] = -sb * s;
    u[6] =  ca * c; u[7] =  sa * c;
    float t2 = 0.5f * ld(crx, tid, fcrx);
    gCS[tid * 2 + 0] = cosf(t2);
    gCS[tid * 2 + 1] = sinf(t2);
  }
  __syncthreads();
}

__device__ __forceinline__ void run_circuit(float (&sr)[8], float (&si)[8],
                                            const float* gU, const float* gCS) {
#pragma unroll 1
  for (int n = 0; n < NL; ++n) {
    const float* U  = gU  + n * NQ * 8;
    const float* CS = gCS + n * NQ * 2;
    rot_x<32>(sr, si, U + 0 * 8);
    rot_x<16>(sr, si, U + 1 * 8);
    rot_x< 8>(sr, si, U + 2 * 8);
    rot_x< 4>(sr, si, U + 3 * 8);
    rot_x< 2>(sr, si, U + 4 * 8);
    rot_x< 1>(sr, si, U + 5 * 8);
    rot_r< 4>(sr, si, U + 6 * 8);
    rot_r< 2>(sr, si, U + 7 * 8);
    rot_r< 1>(sr, si, U + 8 * 8);
    crx_ll<32, 16>(sr, si, CS + 0 * 2);
    crx_ll<16,  8>(sr, si, CS + 1 * 2);
    crx_ll< 8,  4>(sr, si, CS + 2 * 2);
    crx_ll< 4,  2>(sr, si, CS + 3 * 2);
    crx_ll< 2,  1>(sr, si, CS + 4 * 2);
    crx_lr< 1,  4>(sr, si, CS + 5 * 2);
    crx_rr< 2,  2>(sr, si, CS + 6 * 2);
    crx_rr< 1,  1>(sr, si, CS + 7 * 2);
    crx_rl< 0, 32>(sr, si, CS + 8 * 2);
  }
}

// -------- fused prep kernel: blocks 0..127 build W columns (latency-bound),
// -------- blocks 128.. cast x->bf16 (BW-bound) and fill the idle SIMDs -----
__global__ __launch_bounds__(256) void prep_kernel(const void* __restrict__ x,
                                                   const void* __restrict__ rot,
                                                   const void* __restrict__ crx,
                                                   __hip_bfloat16* __restrict__ A,
                                                   __hip_bfloat16* __restrict__ BT) {
  int tid = threadIdx.x;
  if (blockIdx.x < 128) {
    // ---- W build: wave k simulates basis state e_k ----
    __shared__ __align__(16) float gU[NL * NQ * 8];
    __shared__ __align__(16) float gCS[NL * NQ * 2];
    build_gates(rot, crx, gU, gCS);
    int k = (blockIdx.x * 256 + tid) >> 6;  // basis index 0..511
    int lane = tid & 63;
    float sr[8], si[8];
#pragma unroll
    for (int r = 0; r < 8; ++r) {
      sr[r] = (lane * 8 + r == k) ? 1.0f : 0.0f;
      si[r] = 0.0f;
    }
    run_circuit(sr, si, gU, gCS);
#pragma unroll
    for (int r = 0; r < 8; ++r) {
      int j = lane * 8 + r;
      BT[(size_t)j * DIM + k]         = __float2bfloat16(sr[r]);  // Re W[j,k]
      BT[(size_t)(DIM + j) * DIM + k] = __float2bfloat16(si[r]);  // Im W[j,k]
    }
  } else {
    // ---- cast x -> bf16 A ----
    __shared__ int fx;
    if (tid == 0) fx = looks_bf16(x, B_TOT * DIM);
    __syncthreads();
    size_t i0 = ((size_t)(blockIdx.x - 128) * 256 + tid) * 8;  // 8 elems/thread
    if (fx) {
      *(uint4*)(A + i0) = *(const uint4*)((const unsigned short*)x + i0);
    } else {
      const float4* src = (const float4*)((const float*)x + i0);
      float4 a = src[0], b = src[1];
      __hip_bfloat16 o[8];
      o[0] = __float2bfloat16(a.x); o[1] = __float2bfloat16(a.y);
      o[2] = __float2bfloat16(a.z); o[3] = __float2bfloat16(a.w);
      o[4] = __float2bfloat16(b.x); o[5] = __float2bfloat16(b.y);
      o[6] = __float2bfloat16(b.z); o[7] = __float2bfloat16(b.w);
      *(uint4*)(A + i0) = *(uint4*)o;
    }
  }
}

// ---------------- GEMM: C = A x BT' (bf16 MFMA), XCD-aware swizzle ---------
// M=16384, N=1024, K=512.  128x128 tile, 4 waves 2x2, 16x16x32 bf16 MFMA.
// bid%8 = presumed XCD -> owns m-chunk of 2048 rows (A-chunk 2MB + B 1MB < 4MB L2),
// n fastest within a chunk so the B panel and A panels get L2 reuse.
using frag8 = __attribute__((ext_vector_type(8))) short;
using frag4 = __attribute__((ext_vector_type(4))) float;
#define LDP 40  // lds row pitch (bf16): rows hit bank 20r%32 -> only 2-way alias (free)

__global__ __launch_bounds__(256) void gemm_kernel(const unsigned short* __restrict__ A,
                                                   const unsigned short* __restrict__ BT,
                                                   float* __restrict__ C) {
  __shared__ __align__(16) unsigned short lA[128 * LDP];
  __shared__ __align__(16) unsigned short lB[128 * LDP];
  int bid = blockIdx.x;
  int xcd = bid & 7;
  int slot = bid >> 3;                       // 0..127
  int n0 = (slot & 7) * 128;                 // n fastest
  int m0 = (xcd * 16 + (slot >> 3)) * 128;   // xcd owns rows [xcd*2048, +2048)
  int tid = threadIdx.x;
  int wid = tid >> 6, lane = tid & 63;
  int wm = wid >> 1, wn = wid & 1;
  int row = lane & 15, quad = lane >> 4;
  frag4 acc[4][4] = {};
#pragma unroll 1
  for (int k0 = 0; k0 < 512; k0 += 32) {
    __syncthreads();
#pragma unroll
    for (int s = tid; s < 512; s += 256) {  // 128 rows x 4 chunks of 16B
      int rr = s >> 2, cc = s & 3;
      *(uint4*)(&lA[rr * LDP + cc * 8]) =
          *(const uint4*)(&A[(size_t)(m0 + rr) * 512 + k0 + cc * 8]);
      *(uint4*)(&lB[rr * LDP + cc * 8]) =
          *(const uint4*)(&BT[(size_t)(n0 + rr) * 512 + k0 + cc * 8]);
    }
    __syncthreads();
    frag8 af[4], bf[4];
#pragma unroll
    for (int i = 0; i < 4; ++i) {
      af[i] = *(const frag8*)(&lA[(wm * 64 + i * 16 + row) * LDP + quad * 8]);
      bf[i] = *(const frag8*)(&lB[(wn * 64 + i * 16 + row) * LDP + quad * 8]);
    }
#pragma unroll
    for (int mi = 0; mi < 4; ++mi)
#pragma unroll
      for (int ni = 0; ni < 4; ++ni)
        acc[mi][ni] = __builtin_amdgcn_mfma_f32_16x16x32_bf16(af[mi], bf[ni],
                                                              acc[mi][ni], 0, 0, 0);
  }
  // C/D layout: col = lane&15, row = (lane>>4)*4 + reg   [m89/m91 verified]
#pragma unroll
  for (int mi = 0; mi < 4; ++mi)
#pragma unroll
    for (int ni = 0; ni < 4; ++ni)
#pragma unroll
      for (int rg = 0; rg < 4; ++rg) {
        int m = m0 + wm * 64 + mi * 16 + quad * 4 + rg;
        int n = n0 + wn * 64 + ni * 16 + row;
        C[(size_t)m * 1024 + n] = acc[mi][ni][rg];
      }
}

// ---------------- epilogue: probs -> z -> logits -> log_softmax ------------
__global__ __launch_bounds__(256) void epi_kernel(const float* __restrict__ C,
                                                  const void* __restrict__ fcw,
                                                  const void* __restrict__ fcb,
                                                  float* __restrict__ out) {
  __shared__ int flags[2];
  int tid = threadIdx.x;
  if (tid == 0) {
    flags[0] = looks_bf16(fcw, NCLS * NQ);
    flags[1] = looks_bf16(fcb, NCLS);
  }
  __syncthreads();
  int b = (blockIdx.x * 256 + tid) >> 6;
  int lane = tid & 63;
  const float* rowp = C + (size_t)b * 1024;
  const float4* pr4 = (const float4*)(rowp + lane * 8);
  const float4* pi4 = (const float4*)(rowp + 512 + lane * 8);
  float4 r0 = pr4[0], r1 = pr4[1], i0 = pi4[0], i1 = pi4[1];
  float cr[8] = {r0.x, r0.y, r0.z, r0.w, r1.x, r1.y, r1.z, r1.w};
  float ci[8] = {i0.x, i0.y, i0.z, i0.w, i1.x, i1.y, i1.z, i1.w};
  float p[8], P = 0.f;
#pragma unroll
  for (int r = 0; r < 8; ++r) { p[r] = cr[r] * cr[r] + ci[r] * ci[r]; P += p[r]; }
  float z[NQ + 1];
#pragma unroll
  for (int q = 0; q < 6; ++q) z[q] = (lane & (32 >> q)) ? -P : P;
  z[6] = z[7] = z[8] = 0.f;
#pragma unroll
  for (int r = 0; r < 8; ++r) {
    z[6] += (r & 4) ? -p[r] : p[r];
    z[7] += (r & 2) ? -p[r] : p[r];
    z[8] += (r & 1) ? -p[r] : p[r];
  }
  z[9] = P;  // total norm^2 (unitary preserves norm; input unnormalized)
#pragma unroll
  for (int m = 1; m < 64; m <<= 1) {
#pragma unroll
    for (int q = 0; q < NQ + 1; ++q) z[q] += shx(z[q], m);
  }
  float invP = 1.0f / z[9];
#pragma unroll
  for (int q = 0; q < NQ; ++q) z[q] *= invP;
  int ffw = flags[0], ffb = flags[1];
  float lg[NCLS], mx = -1e30f;
#pragma unroll
  for (int k = 0; k < NCLS; ++k) {
    float t = ld(fcb, k, ffb);
#pragma unroll
    for (int q = 0; q < NQ; ++q) t += z[q] * ld(fcw, k * NQ + q, ffw);
    lg[k] = t; mx = fmaxf(mx, t);
  }
  float se = 0.f;
#pragma unroll
  for (int k = 0; k < NCLS; ++k) se += expf(lg[k] - mx);
  float lse = mx + logf(se);
  if (lane < NCLS) out[(size_t)b * NCLS + lane] = lg[lane] - lse;
}

// ---------------- fallback: round-3 passing monolithic kernel --------------
__global__ __launch_bounds__(256) void qnn_kernel(
    const void* __restrict__ x, const void* __restrict__ rot,
    const void* __restrict__ crx, const void* __restrict__ fcw,
    const void* __restrict__ fcb, float* __restrict__ out) {
  __shared__ __align__(16) float gU[NL * NQ * 8];
  __shared__ __align__(16) float gCS[NL * NQ * 2];
  __shared__ int flags[3];
  int tid = threadIdx.x;
  if (tid == 0) {
    flags[0] = looks_bf16(x, B_TOT * DIM);
    flags[1] = looks_bf16(fcw, NCLS * NQ);
    flags[2] = looks_bf16(fcb, NCLS);
  }
  build_gates(rot, crx, gU, gCS);
  __syncthreads();
  int wid = (blockIdx.x * blockDim.x + tid) >> 6;
  int lane = tid & 63;
  float sr[8], si[8];
  if (flags[0]) {
    const uint4 u = *(const uint4*)((const unsigned short*)x + (size_t)wid * DIM + lane * 8);
    sr[0] = __uint_as_float(u.x << 16); sr[1] = __uint_as_float(u.x & 0xffff0000u);
    sr[2] = __uint_as_float(u.y << 16); sr[3] = __uint_as_float(u.y & 0xffff0000u);
    sr[4] = __uint_as_float(u.z << 16); sr[5] = __uint_as_float(u.z & 0xffff0000u);
    sr[6] = __uint_as_float(u.w << 16); sr[7] = __uint_as_float(u.w & 0xffff0000u);
  } else {
    const float4* xf = (const float4*)((const float*)x + (size_t)wid * DIM) + lane * 2;
    float4 a = xf[0], b = xf[1];
    sr[0] = a.x; sr[1] = a.y; sr[2] = a.z; sr[3] = a.w;
    sr[4] = b.x; sr[5] = b.y; sr[6] = b.z; sr[7] = b.w;
  }
  float nrm = 0.f;
#pragma unroll
  for (int r = 0; r < 8; ++r) { nrm += sr[r] * sr[r]; si[r] = 0.f; }
#pragma unroll
  for (int m = 1; m < 64; m <<= 1) nrm += shx(nrm, m);
  float inv = rsqrtf(nrm);
  inv = inv * (1.5f - 0.5f * nrm * inv * inv);
#pragma unroll
  for (int r = 0; r < 8; ++r) sr[r] *= inv;
  run_circuit(sr, si, gU, gCS);
  float p[8], P = 0.f;
#pragma unroll
  for (int r = 0; r < 8; ++r) { p[r] = sr[r] * sr[r] + si[r] * si[r]; P += p[r]; }
  float z[NQ];
#pragma unroll
  for (int q = 0; q < 6; ++q) z[q] = (lane & (32 >> q)) ? -P : P;
  z[6] = z[7] = z[8] = 0.f;
#pragma unroll
  for (int r = 0; r < 8; ++r) {
    z[6] += (r & 4) ? -p[r] : p[r];
    z[7] += (r & 2) ? -p[r] : p[r];
    z[8] += (r & 1) ? -p[r] : p[r];
  }
#pragma unroll
  for (int m = 1; m < 64; m <<= 1) {
#pragma unroll
    for (int q = 0; q < NQ; ++q) z[q] += shx(z[q], m);
  }
  int ffw = flags[1], ffb = flags[2];
  float lg[NCLS], mx = -1e30f;
#pragma unroll
  for (int k = 0; k < NCLS; ++k) {
    float t = ld(fcb, k, ffb);
#pragma unroll
    for (int q = 0; q < NQ; ++q) t += z[q] * ld(fcw, k * NQ + q, ffw);
    lg[k] = t; mx = fmaxf(mx, t);
  }
  float se = 0.f;
#pragma unroll
  for (int k = 0; k < NCLS; ++k) se += expf(lg[k] - mx);
  float lse = mx + logf(se);
  if (lane < NCLS) out[(size_t)wid * NCLS + lane] = lg[lane] - lse;
}

extern "C" void kernel_launch(void* const* d_in, const int* in_sizes, int n_in,
                              void* d_out, int out_size, void* d_ws, size_t ws_size,
                              hipStream_t stream) {
  const void* x   = d_in[0];
  const void* rot = d_in[1];
  const void* crx = d_in[2];
  const void* fcw = d_in[3];
  const void* fcb = d_in[4];
  float* out = (float*)d_out;
  if (ws_size >= WS_NEED) {
    __hip_bfloat16* A  = (__hip_bfloat16*)((char*)d_ws + A_OFF);
    __hip_bfloat16* BT = (__hip_bfloat16*)((char*)d_ws + BT_OFF);
    float*          C  = (float*)((char*)d_ws + C_OFF);
    // fused: 128 wbuild blocks (critical path, dispatched first) + 4096 cast blocks
    prep_kernel<<<128 + (B_TOT * DIM) / (256 * 8), 256, 0, stream>>>(x, rot, crx, A, BT);
    gemm_kernel<<<(B_TOT / 128) * (1024 / 128), 256, 0, stream>>>(
        (const unsigned short*)A, (const unsigned short*)BT, C);
    epi_kernel<<<(B_TOT * 64) / 256, 256, 0, stream>>>(C, fcw, fcb, out);
  } else {
    qnn_kernel<<<(B_TOT * 64) / 256, 256, 0, stream>>>(x, rot, crx, fcw, fcb, out);
  }
}

// Round 6
// 193.421 us; speedup vs baseline: 2.5445x; 1.0057x over previous
//
#include <hip/hip_runtime.h>
#include <hip/hip_bf16.h>
#include <math.h>

#define NQ 9
#define NL 10
#define DIM 512
#define NCLS 10
#define B_TOT 16384

// ws layout (bytes): A bf16 [16384x512] @ 0 (16MB); BT bf16 [1024x512] @ 16MB (1MB);
// C f32 [16384x1024] @ 32MB (64MB).  Need 96MB; else fall back to mono kernel.
#define A_OFF   ((size_t)0)
#define BT_OFF  ((size_t)16 << 20)
#define C_OFF   ((size_t)32 << 20)
#define WS_NEED (((size_t)96) << 20)

__device__ __forceinline__ float shx(float v, int m) { return __shfl_xor(v, m, 64); }

__device__ __forceinline__ int looks_bf16(const void* p, int count) {
  const unsigned short* u = (const unsigned short*)p;
  int n = count < 64 ? count : 64;
  int good = 0;
  for (int i = 0; i < n; ++i) {
    unsigned short v = u[i];
    int e = (v >> 7) & 0xFF;
    good += (e >= 100 && e <= 140) || ((v & 0x7FFF) == 0);
  }
  return good * 8 >= n * 7;
}

__device__ __forceinline__ float ld(const void* p, int i, int isbf) {
  if (isbf) return __uint_as_float(((unsigned)((const unsigned short*)p)[i]) << 16);
  return ((const float*)p)[i];
}

// ---------------- verified gate helpers (round-3, unchanged) ---------------
template<int M>
__device__ __forceinline__ void rot_x(float (&sr)[8], float (&si)[8], const float* u) {
  float4 uA = *(const float4*)u;
  float4 uB = *(const float4*)(u + 4);
  bool hi = (threadIdx.x & M) != 0;
  float ar = hi ? uB.z : uA.x, ai = hi ? uB.w : uA.y;
  float br = hi ? uB.x : uA.z, bi = hi ? uB.y : uA.w;
#pragma unroll
  for (int r = 0; r < 8; ++r) {
    float pr = shx(sr[r], M), pi = shx(si[r], M);
    float nr = ar * sr[r] - ai * si[r] + br * pr - bi * pi;
    float ni = ar * si[r] + ai * sr[r] + br * pi + bi * pr;
    sr[r] = nr; si[r] = ni;
  }
}
template<int S>
__device__ __forceinline__ void rot_r(float (&sr)[8], float (&si)[8], const float* u) {
  float4 uA = *(const float4*)u;
  float4 uB = *(const float4*)(u + 4);
#pragma unroll
  for (int r0 = 0; r0 < 8; ++r0) {
    if (r0 & S) continue;
    int r1 = r0 + S;
    float a0r = sr[r0], a0i = si[r0], a1r = sr[r1], a1i = si[r1];
    sr[r0] = uA.x * a0r - uA.y * a0i + uA.z * a1r - uA.w * a1i;
    si[r0] = uA.x * a0i + uA.y * a0r + uA.z * a1i + uA.w * a1r;
    sr[r1] = uB.x * a0r - uB.y * a0i + uB.z * a1r - uB.w * a1i;
    si[r1] = uB.x * a0i + uB.y * a0r + uB.z * a1i + uB.w * a1r;
  }
}
template<int MC, int MT>
__device__ __forceinline__ void crx_ll(float (&sr)[8], float (&si)[8], const float* cs) {
  bool ctrl = (threadIdx.x & MC) != 0;
  float c = ctrl ? cs[0] : 1.0f;
  float s = ctrl ? cs[1] : 0.0f;
#pragma unroll
  for (int r = 0; r < 8; ++r) {
    float pr = shx(sr[r], MT), pi = shx(si[r], MT);
    float nr = c * sr[r] + s * pi;
    float ni = c * si[r] - s * pr;
    sr[r] = nr; si[r] = ni;
  }
}
template<int MC, int ST>
__device__ __forceinline__ void crx_lr(float (&sr)[8], float (&si)[8], const float* cs) {
  bool ctrl = (threadIdx.x & MC) != 0;
  float c = ctrl ? cs[0] : 1.0f;
  float s = ctrl ? cs[1] : 0.0f;
#pragma unroll
  for (int r0 = 0; r0 < 8; ++r0) {
    if (r0 & ST) continue;
    int r1 = r0 + ST;
    float a0r = sr[r0], a0i = si[r0], a1r = sr[r1], a1i = si[r1];
    sr[r0] = c * a0r + s * a1i;  si[r0] = c * a0i - s * a1r;
    sr[r1] = c * a1r + s * a0i;  si[r1] = c * a1i - s * a0r;
  }
}
template<int PC, int ST>
__device__ __forceinline__ void crx_rr(float (&sr)[8], float (&si)[8], const float* cs) {
  float c = cs[0], s = cs[1];
#pragma unroll
  for (int r0 = 0; r0 < 8; ++r0) {
    if (r0 & ST) continue;
    if (!((r0 >> PC) & 1)) continue;
    int r1 = r0 + ST;
    float a0r = sr[r0], a0i = si[r0], a1r = sr[r1], a1i = si[r1];
    sr[r0] = c * a0r + s * a1i;  si[r0] = c * a0i - s * a1r;
    sr[r1] = c * a1r + s * a0i;  si[r1] = c * a1i - s * a0r;
  }
}
template<int PC, int MT>
__device__ __forceinline__ void crx_rl(float (&sr)[8], float (&si)[8], const float* cs) {
  float c = cs[0], s = cs[1];
#pragma unroll
  for (int r = 0; r < 8; ++r) {
    if (!((r >> PC) & 1)) continue;
    float pr = shx(sr[r], MT), pi = shx(si[r], MT);
    float nr = c * sr[r] + s * pi;
    float ni = c * si[r] - s * pr;
    sr[r] = nr; si[r] = ni;
  }
}

__device__ __forceinline__ void build_gates(const void* rot, const void* crx,
                                            float* gU, float* gCS) {
  int tid = threadIdx.x;
  __shared__ int gflags[2];
  if (tid == 0) {
    gflags[0] = looks_bf16(rot, NL * NQ * 3);
    gflags[1] = looks_bf16(crx, NL * NQ);
  }
  __syncthreads();
  if (tid < NL * NQ) {
    int frot = gflags[0], fcrx = gflags[1];
    float phi = ld(rot, tid * 3 + 0, frot);
    float th  = ld(rot, tid * 3 + 1, frot);
    float om  = ld(rot, tid * 3 + 2, frot);
    float c = cosf(0.5f * th), s = sinf(0.5f * th);
    float a = 0.5f * (phi + om), b = 0.5f * (phi - om);
    float ca = cosf(a), sa = sinf(a), cb = cosf(b), sb = sinf(b);
    float* u = gU + tid * 8;
    u[0] =  ca * c; u[1] = -sa * c;
    u[2] = -cb * s; u[3] = -sb * s;
    u[4] =  cb * s; u[5] = -sb * s;
    u[6] =  ca * c; u[7] =  sa * c;
    float t2 = 0.5f * ld(crx, tid, fcrx);
    gCS[tid * 2 + 0] = cosf(t2);
    gCS[tid * 2 + 1] = sinf(t2);
  }
  __syncthreads();
}

__device__ __forceinline__ void run_circuit(float (&sr)[8], float (&si)[8],
                                            const float* gU, const float* gCS) {
#pragma unroll 1
  for (int n = 0; n < NL; ++n) {
    const float* U  = gU  + n * NQ * 8;
    const float* CS = gCS + n * NQ * 2;
    rot_x<32>(sr, si, U + 0 * 8);
    rot_x<16>(sr, si, U + 1 * 8);
    rot_x< 8>(sr, si, U + 2 * 8);
    rot_x< 4>(sr, si, U + 3 * 8);
    rot_x< 2>(sr, si, U + 4 * 8);
    rot_x< 1>(sr, si, U + 5 * 8);
    rot_r< 4>(sr, si, U + 6 * 8);
    rot_r< 2>(sr, si, U + 7 * 8);
    rot_r< 1>(sr, si, U + 8 * 8);
    crx_ll<32, 16>(sr, si, CS + 0 * 2);
    crx_ll<16,  8>(sr, si, CS + 1 * 2);
    crx_ll< 8,  4>(sr, si, CS + 2 * 2);
    crx_ll< 4,  2>(sr, si, CS + 3 * 2);
    crx_ll< 2,  1>(sr, si, CS + 4 * 2);
    crx_lr< 1,  4>(sr, si, CS + 5 * 2);
    crx_rr< 2,  2>(sr, si, CS + 6 * 2);
    crx_rr< 1,  1>(sr, si, CS + 7 * 2);
    crx_rl< 0, 32>(sr, si, CS + 8 * 2);
  }
}

// -------- fused prep kernel: blocks 0..127 build W columns (latency-bound),
// -------- blocks 128.. cast x->bf16 (BW-bound) and fill the idle SIMDs -----
__global__ __launch_bounds__(256) void prep_kernel(const void* __restrict__ x,
                                                   const void* __restrict__ rot,
                                                   const void* __restrict__ crx,
                                                   __hip_bfloat16* __restrict__ A,
                                                   __hip_bfloat16* __restrict__ BT) {
  int tid = threadIdx.x;
  if (blockIdx.x < 128) {
    __shared__ __align__(16) float gU[NL * NQ * 8];
    __shared__ __align__(16) float gCS[NL * NQ * 2];
    build_gates(rot, crx, gU, gCS);
    int k = (blockIdx.x * 256 + tid) >> 6;  // basis index 0..511
    int lane = tid & 63;
    float sr[8], si[8];
#pragma unroll
    for (int r = 0; r < 8; ++r) {
      sr[r] = (lane * 8 + r == k) ? 1.0f : 0.0f;
      si[r] = 0.0f;
    }
    run_circuit(sr, si, gU, gCS);
#pragma unroll
    for (int r = 0; r < 8; ++r) {
      int j = lane * 8 + r;
      BT[(size_t)j * DIM + k]         = __float2bfloat16(sr[r]);  // Re W[j,k]
      BT[(size_t)(DIM + j) * DIM + k] = __float2bfloat16(si[r]);  // Im W[j,k]
    }
  } else {
    __shared__ int fx;
    if (tid == 0) fx = looks_bf16(x, B_TOT * DIM);
    __syncthreads();
    size_t i0 = ((size_t)(blockIdx.x - 128) * 256 + tid) * 8;  // 8 elems/thread
    if (fx) {
      *(uint4*)(A + i0) = *(const uint4*)((const unsigned short*)x + i0);
    } else {
      const float4* src = (const float4*)((const float*)x + i0);
      float4 a = src[0], b = src[1];
      __hip_bfloat16 o[8];
      o[0] = __float2bfloat16(a.x); o[1] = __float2bfloat16(a.y);
      o[2] = __float2bfloat16(a.z); o[3] = __float2bfloat16(a.w);
      o[4] = __float2bfloat16(b.x); o[5] = __float2bfloat16(b.y);
      o[6] = __float2bfloat16(b.z); o[7] = __float2bfloat16(b.w);
      *(uint4*)(A + i0) = *(uint4*)o;
    }
  }
}

// ---------------- GEMM: C = A x BT' (bf16 MFMA), m97-style staging ---------
// M=16384, N=1024, K=512.  128x128 tile, 4 waves 2x2, 16x16x32 bf16 MFMA.
// Staging via global_load_lds width=16 (m93->m97 = 517->874 TF on the ladder).
// LDS is UNPADDED [128][32]: async-copy dest is wave-uniform base + lane*16,
// lane-contiguous row-major mapping (16B = 8 bf16 = quarter row of BK=32).
using frag8 = __attribute__((ext_vector_type(8))) short;
using frag4 = __attribute__((ext_vector_type(4))) float;

typedef __attribute__((address_space(1))) const unsigned int GU32;
typedef __attribute__((address_space(3))) unsigned int LU32;
__device__ __forceinline__ void async16(const void* g, void* l) {
  __builtin_amdgcn_global_load_lds((GU32*)g, (LU32*)l, 16, 0, 0);
}

__global__ __launch_bounds__(256) void gemm_kernel(const unsigned short* __restrict__ A,
                                                   const unsigned short* __restrict__ BT,
                                                   float* __restrict__ C) {
  __shared__ __align__(16) unsigned short lA[128 * 32];
  __shared__ __align__(16) unsigned short lB[128 * 32];
  int bid = blockIdx.x;
  int xcd = bid & 7;
  int slot = bid >> 3;                       // 0..127
  int n0 = (slot & 7) * 128;                 // n fastest
  int m0 = (xcd * 16 + (slot >> 3)) * 128;   // xcd owns rows [xcd*2048, +2048)
  int tid = threadIdx.x;
  int wv = tid >> 6, lane = tid & 63;
  int wm = wv >> 1, wn = wv & 1;
  int row = lane & 15, quad = lane >> 4;
  // staging addresses: wave wv fills rows [wv*32, wv*32+32) of lA and lB;
  // call t covers 16 rows: lane -> row (lane>>2), k-chunk (lane&3)*8 elems.
  int srow = wv * 32 + (lane >> 2);
  int scol = (lane & 3) * 8;
  const unsigned short* gA = A + (size_t)(m0 + srow) * 512 + scol;
  const unsigned short* gB = BT + (size_t)(n0 + srow) * 512 + scol;
  frag4 acc[4][4] = {};
#pragma unroll 1
  for (int k0 = 0; k0 < 512; k0 += 32) {
    __syncthreads();
    async16(gA + k0,            &lA[(wv * 32) * 32]);
    async16(gA + k0 + 16 * 512, &lA[(wv * 32 + 16) * 32]);
    async16(gB + k0,            &lB[(wv * 32) * 32]);
    async16(gB + k0 + 16 * 512, &lB[(wv * 32 + 16) * 32]);
    __syncthreads();  // vmcnt(0) drain + barrier (m97 structure)
    frag8 af[4], bf[4];
#pragma unroll
    for (int i = 0; i < 4; ++i) {
      af[i] = *(const frag8*)(&lA[(wm * 64 + i * 16 + row) * 32 + quad * 8]);
      bf[i] = *(const frag8*)(&lB[(wn * 64 + i * 16 + row) * 32 + quad * 8]);
    }
#pragma unroll
    for (int mi = 0; mi < 4; ++mi)
#pragma unroll
      for (int ni = 0; ni < 4; ++ni)
        acc[mi][ni] = __builtin_amdgcn_mfma_f32_16x16x32_bf16(af[mi], bf[ni],
                                                              acc[mi][ni], 0, 0, 0);
  }
  // C/D layout: col = lane&15, row = (lane>>4)*4 + reg   [m89/m91 verified]
#pragma unroll
  for (int mi = 0; mi < 4; ++mi)
#pragma unroll
    for (int ni = 0; ni < 4; ++ni)
#pragma unroll
      for (int rg = 0; rg < 4; ++rg) {
        int m = m0 + wm * 64 + mi * 16 + quad * 4 + rg;
        int n = n0 + wn * 64 + ni * 16 + row;
        C[(size_t)m * 1024 + n] = acc[mi][ni][rg];
      }
}

// ---------------- epilogue: probs -> z -> logits -> log_softmax ------------
__global__ __launch_bounds__(256) void epi_kernel(const float* __restrict__ C,
                                                  const void* __restrict__ fcw,
                                                  const void* __restrict__ fcb,
                                                  float* __restrict__ out) {
  __shared__ int flags[2];
  int tid = threadIdx.x;
  if (tid == 0) {
    flags[0] = looks_bf16(fcw, NCLS * NQ);
    flags[1] = looks_bf16(fcb, NCLS);
  }
  __syncthreads();
  int b = (blockIdx.x * 256 + tid) >> 6;
  int lane = tid & 63;
  const float* rowp = C + (size_t)b * 1024;
  const float4* pr4 = (const float4*)(rowp + lane * 8);
  const float4* pi4 = (const float4*)(rowp + 512 + lane * 8);
  float4 r0 = pr4[0], r1 = pr4[1], i0 = pi4[0], i1 = pi4[1];
  float cr[8] = {r0.x, r0.y, r0.z, r0.w, r1.x, r1.y, r1.z, r1.w};
  float ci[8] = {i0.x, i0.y, i0.z, i0.w, i1.x, i1.y, i1.z, i1.w};
  float p[8], P = 0.f;
#pragma unroll
  for (int r = 0; r < 8; ++r) { p[r] = cr[r] * cr[r] + ci[r] * ci[r]; P += p[r]; }
  float z[NQ + 1];
#pragma unroll
  for (int q = 0; q < 6; ++q) z[q] = (lane & (32 >> q)) ? -P : P;
  z[6] = z[7] = z[8] = 0.f;
#pragma unroll
  for (int r = 0; r < 8; ++r) {
    z[6] += (r & 4) ? -p[r] : p[r];
    z[7] += (r & 2) ? -p[r] : p[r];
    z[8] += (r & 1) ? -p[r] : p[r];
  }
  z[9] = P;  // total norm^2 (unitary preserves norm; input unnormalized)
#pragma unroll
  for (int m = 1; m < 64; m <<= 1) {
#pragma unroll
    for (int q = 0; q < NQ + 1; ++q) z[q] += shx(z[q], m);
  }
  float invP = 1.0f / z[9];
#pragma unroll
  for (int q = 0; q < NQ; ++q) z[q] *= invP;
  int ffw = flags[0], ffb = flags[1];
  float lg[NCLS], mx = -1e30f;
#pragma unroll
  for (int k = 0; k < NCLS; ++k) {
    float t = ld(fcb, k, ffb);
#pragma unroll
    for (int q = 0; q < NQ; ++q) t += z[q] * ld(fcw, k * NQ + q, ffw);
    lg[k] = t; mx = fmaxf(mx, t);
  }
  float se = 0.f;
#pragma unroll
  for (int k = 0; k < NCLS; ++k) se += expf(lg[k] - mx);
  float lse = mx + logf(se);
  if (lane < NCLS) out[(size_t)b * NCLS + lane] = lg[lane] - lse;
}

// ---------------- fallback: round-3 passing monolithic kernel --------------
__global__ __launch_bounds__(256) void qnn_kernel(
    const void* __restrict__ x, const void* __restrict__ rot,
    const void* __restrict__ crx, const void* __restrict__ fcw,
    const void* __restrict__ fcb, float* __restrict__ out) {
  __shared__ __align__(16) float gU[NL * NQ * 8];
  __shared__ __align__(16) float gCS[NL * NQ * 2];
  __shared__ int flags[3];
  int tid = threadIdx.x;
  if (tid == 0) {
    flags[0] = looks_bf16(x, B_TOT * DIM);
    flags[1] = looks_bf16(fcw, NCLS * NQ);
    flags[2] = looks_bf16(fcb, NCLS);
  }
  build_gates(rot, crx, gU, gCS);
  __syncthreads();
  int wid = (blockIdx.x * blockDim.x + tid) >> 6;
  int lane = tid & 63;
  float sr[8], si[8];
  if (flags[0]) {
    const uint4 u = *(const uint4*)((const unsigned short*)x + (size_t)wid * DIM + lane * 8);
    sr[0] = __uint_as_float(u.x << 16); sr[1] = __uint_as_float(u.x & 0xffff0000u);
    sr[2] = __uint_as_float(u.y << 16); sr[3] = __uint_as_float(u.y & 0xffff0000u);
    sr[4] = __uint_as_float(u.z << 16); sr[5] = __uint_as_float(u.z & 0xffff0000u);
    sr[6] = __uint_as_float(u.w << 16); sr[7] = __uint_as_float(u.w & 0xffff0000u);
  } else {
    const float4* xf = (const float4*)((const float*)x + (size_t)wid * DIM) + lane * 2;
    float4 a = xf[0], b = xf[1];
    sr[0] = a.x; sr[1] = a.y; sr[2] = a.z; sr[3] = a.w;
    sr[4] = b.x; sr[5] = b.y; sr[6] = b.z; sr[7] = b.w;
  }
  float nrm = 0.f;
#pragma unroll
  for (int r = 0; r < 8; ++r) { nrm += sr[r] * sr[r]; si[r] = 0.f; }
#pragma unroll
  for (int m = 1; m < 64; m <<= 1) nrm += shx(nrm, m);
  float inv = rsqrtf(nrm);
  inv = inv * (1.5f - 0.5f * nrm * inv * inv);
#pragma unroll
  for (int r = 0; r < 8; ++r) sr[r] *= inv;
  run_circuit(sr, si, gU, gCS);
  float p[8], P = 0.f;
#pragma unroll
  for (int r = 0; r < 8; ++r) { p[r] = sr[r] * sr[r] + si[r] * si[r]; P += p[r]; }
  float z[NQ];
#pragma unroll
  for (int q = 0; q < 6; ++q) z[q] = (lane & (32 >> q)) ? -P : P;
  z[6] = z[7] = z[8] = 0.f;
#pragma unroll
  for (int r = 0; r < 8; ++r) {
    z[6] += (r & 4) ? -p[r] : p[r];
    z[7] += (r & 2) ? -p[r] : p[r];
    z[8] += (r & 1) ? -p[r] : p[r];
  }
#pragma unroll
  for (int m = 1; m < 64; m <<= 1) {
#pragma unroll
    for (int q = 0; q < NQ; ++q) z[q] += shx(z[q], m);
  }
  int ffw = flags[1], ffb = flags[2];
  float lg[NCLS], mx = -1e30f;
#pragma unroll
  for (int k = 0; k < NCLS; ++k) {
    float t = ld(fcb, k, ffb);
#pragma unroll
    for (int q = 0; q < NQ; ++q) t += z[q] * ld(fcw, k * NQ + q, ffw);
    lg[k] = t; mx = fmaxf(mx, t);
  }
  float se = 0.f;
#pragma unroll
  for (int k = 0; k < NCLS; ++k) se += expf(lg[k] - mx);
  float lse = mx + logf(se);
  if (lane < NCLS) out[(size_t)wid * NCLS + lane] = lg[lane] - lse;
}

extern "C" void kernel_launch(void* const* d_in, const int* in_sizes, int n_in,
                              void* d_out, int out_size, void* d_ws, size_t ws_size,
                              hipStream_t stream) {
  const void* x   = d_in[0];
  const void* rot = d_in[1];
  const void* crx = d_in[2];
  const void* fcw = d_in[3];
  const void* fcb = d_in[4];
  float* out = (float*)d_out;
  if (ws_size >= WS_NEED) {
    __hip_bfloat16* A  = (__hip_bfloat16*)((char*)d_ws + A_OFF);
    __hip_bfloat16* BT = (__hip_bfloat16*)((char*)d_ws + BT_OFF);
    float*          C  = (float*)((char*)d_ws + C_OFF);
    prep_kernel<<<128 + (B_TOT * DIM) / (256 * 8), 256, 0, stream>>>(x, rot, crx, A, BT);
    gemm_kernel<<<(B_TOT / 128) * (1024 / 128), 256, 0, stream>>>(
        (const unsigned short*)A, (const unsigned short*)BT, C);
    epi_kernel<<<(B_TOT * 64) / 256, 256, 0, stream>>>(C, fcw, fcb, out);
  } else {
    qnn_kernel<<<(B_TOT * 64) / 256, 256, 0, stream>>>(x, rot, crx, fcw, fcb, out);
  }
}

// Round 7
// 179.382 us; speedup vs baseline: 2.7436x; 1.0783x over previous
//
#include <hip/hip_runtime.h>
#include <hip/hip_bf16.h>
#include <math.h>

#define NQ 9
#define NL 10
#define DIM 512
#define NCLS 10
#define B_TOT 16384

// ws layout (bytes): A bf16 [16384x512] @ 0 (16MB); BT bf16 [1024x512] @ 16MB (1MB);
// C bf16 [16384x1024] @ 32MB (32MB).  Need 96MB headroom check (known OK).
#define A_OFF   ((size_t)0)
#define BT_OFF  ((size_t)16 << 20)
#define C_OFF   ((size_t)32 << 20)
#define WS_NEED (((size_t)96) << 20)

__device__ __forceinline__ float shx(float v, int m) { return __shfl_xor(v, m, 64); }

__device__ __forceinline__ int looks_bf16(const void* p, int count) {
  const unsigned short* u = (const unsigned short*)p;
  int n = count < 64 ? count : 64;
  int good = 0;
  for (int i = 0; i < n; ++i) {
    unsigned short v = u[i];
    int e = (v >> 7) & 0xFF;
    good += (e >= 100 && e <= 140) || ((v & 0x7FFF) == 0);
  }
  return good * 8 >= n * 7;
}

__device__ __forceinline__ float ld(const void* p, int i, int isbf) {
  if (isbf) return __uint_as_float(((unsigned)((const unsigned short*)p)[i]) << 16);
  return ((const float*)p)[i];
}

// ---------------- 8-amp gate helpers (verified R3; used by fallback) -------
template<int M>
__device__ __forceinline__ void rot_x(float (&sr)[8], float (&si)[8], const float* u) {
  float4 uA = *(const float4*)u;
  float4 uB = *(const float4*)(u + 4);
  bool hi = (threadIdx.x & M) != 0;
  float ar = hi ? uB.z : uA.x, ai = hi ? uB.w : uA.y;
  float br = hi ? uB.x : uA.z, bi = hi ? uB.y : uA.w;
#pragma unroll
  for (int r = 0; r < 8; ++r) {
    float pr = shx(sr[r], M), pi = shx(si[r], M);
    float nr = ar * sr[r] - ai * si[r] + br * pr - bi * pi;
    float ni = ar * si[r] + ai * sr[r] + br * pi + bi * pr;
    sr[r] = nr; si[r] = ni;
  }
}
template<int S>
__device__ __forceinline__ void rot_r(float (&sr)[8], float (&si)[8], const float* u) {
  float4 uA = *(const float4*)u;
  float4 uB = *(const float4*)(u + 4);
#pragma unroll
  for (int r0 = 0; r0 < 8; ++r0) {
    if (r0 & S) continue;
    int r1 = r0 + S;
    float a0r = sr[r0], a0i = si[r0], a1r = sr[r1], a1i = si[r1];
    sr[r0] = uA.x * a0r - uA.y * a0i + uA.z * a1r - uA.w * a1i;
    si[r0] = uA.x * a0i + uA.y * a0r + uA.z * a1i + uA.w * a1r;
    sr[r1] = uB.x * a0r - uB.y * a0i + uB.z * a1r - uB.w * a1i;
    si[r1] = uB.x * a0i + uB.y * a0r + uB.z * a1i + uB.w * a1r;
  }
}
template<int MC, int MT>
__device__ __forceinline__ void crx_ll(float (&sr)[8], float (&si)[8], const float* cs) {
  bool ctrl = (threadIdx.x & MC) != 0;
  float c = ctrl ? cs[0] : 1.0f;
  float s = ctrl ? cs[1] : 0.0f;
#pragma unroll
  for (int r = 0; r < 8; ++r) {
    float pr = shx(sr[r], MT), pi = shx(si[r], MT);
    float nr = c * sr[r] + s * pi;
    float ni = c * si[r] - s * pr;
    sr[r] = nr; si[r] = ni;
  }
}
template<int MC, int ST>
__device__ __forceinline__ void crx_lr(float (&sr)[8], float (&si)[8], const float* cs) {
  bool ctrl = (threadIdx.x & MC) != 0;
  float c = ctrl ? cs[0] : 1.0f;
  float s = ctrl ? cs[1] : 0.0f;
#pragma unroll
  for (int r0 = 0; r0 < 8; ++r0) {
    if (r0 & ST) continue;
    int r1 = r0 + ST;
    float a0r = sr[r0], a0i = si[r0], a1r = sr[r1], a1i = si[r1];
    sr[r0] = c * a0r + s * a1i;  si[r0] = c * a0i - s * a1r;
    sr[r1] = c * a1r + s * a0i;  si[r1] = c * a1i - s * a0r;
  }
}
template<int PC, int ST>
__device__ __forceinline__ void crx_rr(float (&sr)[8], float (&si)[8], const float* cs) {
  float c = cs[0], s = cs[1];
#pragma unroll
  for (int r0 = 0; r0 < 8; ++r0) {
    if (r0 & ST) continue;
    if (!((r0 >> PC) & 1)) continue;
    int r1 = r0 + ST;
    float a0r = sr[r0], a0i = si[r0], a1r = sr[r1], a1i = si[r1];
    sr[r0] = c * a0r + s * a1i;  si[r0] = c * a0i - s * a1r;
    sr[r1] = c * a1r + s * a0i;  si[r1] = c * a1i - s * a0r;
  }
}
template<int PC, int MT>
__device__ __forceinline__ void crx_rl(float (&sr)[8], float (&si)[8], const float* cs) {
  float c = cs[0], s = cs[1];
#pragma unroll
  for (int r = 0; r < 8; ++r) {
    if (!((r >> PC) & 1)) continue;
    float pr = shx(sr[r], MT), pi = shx(si[r], MT);
    float nr = c * sr[r] + s * pi;
    float ni = c * si[r] - s * pr;
    sr[r] = nr; si[r] = ni;
  }
}

__device__ __forceinline__ void build_gates(const void* rot, const void* crx,
                                            float* gU, float* gCS) {
  int tid = threadIdx.x;
  __shared__ int gflags[2];
  if (tid == 0) {
    gflags[0] = looks_bf16(rot, NL * NQ * 3);
    gflags[1] = looks_bf16(crx, NL * NQ);
  }
  __syncthreads();
  if (tid < NL * NQ) {
    int frot = gflags[0], fcrx = gflags[1];
    float phi = ld(rot, tid * 3 + 0, frot);
    float th  = ld(rot, tid * 3 + 1, frot);
    float om  = ld(rot, tid * 3 + 2, frot);
    float c = cosf(0.5f * th), s = sinf(0.5f * th);
    float a = 0.5f * (phi + om), b = 0.5f * (phi - om);
    float ca = cosf(a), sa = sinf(a), cb = cosf(b), sb = sinf(b);
    float* u = gU + tid * 8;
    u[0] =  ca * c; u[1] = -sa * c;
    u[2] = -cb * s; u[3] = -sb * s;
    u[4] =  cb * s; u[5] = -sb * s;
    u[6] =  ca * c; u[7] =  sa * c;
    float t2 = 0.5f * ld(crx, tid, fcrx);
    gCS[tid * 2 + 0] = cosf(t2);
    gCS[tid * 2 + 1] = sinf(t2);
  }
  __syncthreads();
}

__device__ __forceinline__ void run_circuit(float (&sr)[8], float (&si)[8],
                                            const float* gU, const float* gCS) {
#pragma unroll 1
  for (int n = 0; n < NL; ++n) {
    const float* U  = gU  + n * NQ * 8;
    const float* CS = gCS + n * NQ * 2;
    rot_x<32>(sr, si, U + 0 * 8);
    rot_x<16>(sr, si, U + 1 * 8);
    rot_x< 8>(sr, si, U + 2 * 8);
    rot_x< 4>(sr, si, U + 3 * 8);
    rot_x< 2>(sr, si, U + 4 * 8);
    rot_x< 1>(sr, si, U + 5 * 8);
    rot_r< 4>(sr, si, U + 6 * 8);
    rot_r< 2>(sr, si, U + 7 * 8);
    rot_r< 1>(sr, si, U + 8 * 8);
    crx_ll<32, 16>(sr, si, CS + 0 * 2);
    crx_ll<16,  8>(sr, si, CS + 1 * 2);
    crx_ll< 8,  4>(sr, si, CS + 2 * 2);
    crx_ll< 4,  2>(sr, si, CS + 3 * 2);
    crx_ll< 2,  1>(sr, si, CS + 4 * 2);
    crx_lr< 1,  4>(sr, si, CS + 5 * 2);
    crx_rr< 2,  2>(sr, si, CS + 6 * 2);
    crx_rr< 1,  1>(sr, si, CS + 7 * 2);
    crx_rl< 0, 32>(sr, si, CS + 8 * 2);
  }
}

// ---------------- 2-amp gate helpers (4-wave-per-column wbuild) ------------
// Block = 4 waves = 1 column. amp idx = wv*128 + lane*2 + r.
// bit8,7 = wv; bits 6..1 = lane bits 5..0; bit0 = r.
// qubit q <-> idx bit (8-q): q0,q1 cross-wave; q2..q7 lane (masks 32..1); q8 reg.
template<int M>
__device__ __forceinline__ void rot_lane2(float (&sr)[2], float (&si)[2], const float* u) {
  float4 uA = *(const float4*)u;
  float4 uB = *(const float4*)(u + 4);
  bool hi = (threadIdx.x & M) != 0;  // M<=32: lane bit
  float ar = hi ? uB.z : uA.x, ai = hi ? uB.w : uA.y;
  float br = hi ? uB.x : uA.z, bi = hi ? uB.y : uA.w;
#pragma unroll
  for (int r = 0; r < 2; ++r) {
    float pr = shx(sr[r], M), pi = shx(si[r], M);
    float nr = ar * sr[r] - ai * si[r] + br * pr - bi * pi;
    float ni = ar * si[r] + ai * sr[r] + br * pi + bi * pr;
    sr[r] = nr; si[r] = ni;
  }
}
__device__ __forceinline__ void rot_reg2(float (&sr)[2], float (&si)[2], const float* u) {
  float4 uA = *(const float4*)u;
  float4 uB = *(const float4*)(u + 4);
  float a0r = sr[0], a0i = si[0], a1r = sr[1], a1i = si[1];
  sr[0] = uA.x * a0r - uA.y * a0i + uA.z * a1r - uA.w * a1i;
  si[0] = uA.x * a0i + uA.y * a0r + uA.z * a1i + uA.w * a1r;
  sr[1] = uB.x * a0r - uB.y * a0i + uB.z * a1r - uB.w * a1i;
  si[1] = uB.x * a0i + uB.y * a0r + uB.z * a1i + uB.w * a1r;
}
__device__ __forceinline__ void crx_lane2(float (&sr)[2], float (&si)[2],
                                          float c, float s, int MT) {
#pragma unroll
  for (int r = 0; r < 2; ++r) {
    float pr = shx(sr[r], MT), pi = shx(si[r], MT);
    float nr = c * sr[r] + s * pi;
    float ni = c * si[r] - s * pr;
    sr[r] = nr; si[r] = ni;
  }
}
__device__ __forceinline__ void crx_reg2(float (&sr)[2], float (&si)[2], float c, float s) {
  float a0r = sr[0], a0i = si[0], a1r = sr[1], a1i = si[1];
  sr[0] = c * a0r + s * a1i;  si[0] = c * a0i - s * a1r;
  sr[1] = c * a1r + s * a0i;  si[1] = c * a1i - s * a0r;
}

// -------- fused prep: blocks 0..511 build one W column each (4 waves/col),
// -------- blocks 512.. cast x->bf16 and fill remaining SIMDs ---------------
__global__ __launch_bounds__(256) void prep_kernel(const void* __restrict__ x,
                                                   const void* __restrict__ rot,
                                                   const void* __restrict__ crx,
                                                   __hip_bfloat16* __restrict__ A,
                                                   __hip_bfloat16* __restrict__ BT) {
  int tid = threadIdx.x;
  if (blockIdx.x < DIM) {
    __shared__ __align__(16) float gU[NL * NQ * 8];
    __shared__ __align__(16) float gCS[NL * NQ * 2];
    __shared__ float sRe[DIM], sIm[DIM];
    build_gates(rot, crx, gU, gCS);
    int lane = tid & 63, wv = tid >> 6;
    int idx0 = wv * 128 + lane * 2;
    int k = blockIdx.x;  // column / basis index
    float sr[2], si[2];
    sr[0] = (idx0 == k) ? 1.f : 0.f;
    sr[1] = (idx0 + 1 == k) ? 1.f : 0.f;
    si[0] = si[1] = 0.f;
#pragma unroll 1
    for (int n = 0; n < NL; ++n) {
      const float* U  = gU  + n * NQ * 8;
      const float* CS = gCS + n * NQ * 2;
      // --- composed Rot(q0) x Rot(q1): cross-wave 4x4 on wv bits ---
      __syncthreads();
      sRe[idx0] = sr[0]; sIm[idx0] = si[0];
      sRe[idx0 + 1] = sr[1]; sIm[idx0 + 1] = si[1];
      __syncthreads();
      {
        const float* U0 = U; const float* U1 = U + 8;
        int a = wv >> 1, b = wv & 1;
        float mr[4], mi[4];
#pragma unroll
        for (int w2 = 0; w2 < 4; ++w2) {
          int a2 = w2 >> 1, b2 = w2 & 1;
          float u0r = U0[(a * 2 + a2) * 2], u0i = U0[(a * 2 + a2) * 2 + 1];
          float u1r = U1[(b * 2 + b2) * 2], u1i = U1[(b * 2 + b2) * 2 + 1];
          mr[w2] = u0r * u1r - u0i * u1i;
          mi[w2] = u0r * u1i + u0i * u1r;
        }
#pragma unroll
        for (int r = 0; r < 2; ++r) {
          float nr = 0.f, ni = 0.f;
#pragma unroll
          for (int w2 = 0; w2 < 4; ++w2) {
            float xr = sRe[w2 * 128 + lane * 2 + r];
            float xi = sIm[w2 * 128 + lane * 2 + r];
            nr += mr[w2] * xr - mi[w2] * xi;
            ni += mr[w2] * xi + mi[w2] * xr;
          }
          sr[r] = nr; si[r] = ni;
        }
      }
      // --- Rot q2..q7 (lane), q8 (reg) ---
      rot_lane2<32>(sr, si, U + 2 * 8);
      rot_lane2<16>(sr, si, U + 3 * 8);
      rot_lane2< 8>(sr, si, U + 4 * 8);
      rot_lane2< 4>(sr, si, U + 5 * 8);
      rot_lane2< 2>(sr, si, U + 6 * 8);
      rot_lane2< 1>(sr, si, U + 7 * 8);
      rot_reg2(sr, si, U + 8 * 8);
      // --- CRX(0->1): ctrl wv bit1, target wv bit0 (cross-wave) ---
      __syncthreads();
      sRe[idx0] = sr[0]; sIm[idx0] = si[0];
      sRe[idx0 + 1] = sr[1]; sIm[idx0 + 1] = si[1];
      __syncthreads();
      {
        float c = (wv & 2) ? CS[0] : 1.f, s = (wv & 2) ? CS[1] : 0.f;
        int p0 = (wv ^ 1) * 128 + lane * 2;
#pragma unroll
        for (int r = 0; r < 2; ++r) {
          float pr = sRe[p0 + r], pi = sIm[p0 + r];
          float nr = c * sr[r] + s * pi;
          float ni = c * si[r] - s * pr;
          sr[r] = nr; si[r] = ni;
        }
      }
      // --- CRX(1->2): ctrl wv bit0 (uniform), target lane mask 32 ---
      { float c = (wv & 1) ? CS[2] : 1.f, s = (wv & 1) ? CS[3] : 0.f;
        crx_lane2(sr, si, c, s, 32); }
      // --- CRX(2->3)..(6->7): lane ctrl/target ---
      { bool ct = (lane & 32); crx_lane2(sr, si, ct ? CS[4] : 1.f, ct ? CS[5] : 0.f, 16); }
      { bool ct = (lane & 16); crx_lane2(sr, si, ct ? CS[6] : 1.f, ct ? CS[7] : 0.f, 8); }
      { bool ct = (lane &  8); crx_lane2(sr, si, ct ? CS[8] : 1.f, ct ? CS[9] : 0.f, 4); }
      { bool ct = (lane &  4); crx_lane2(sr, si, ct ? CS[10] : 1.f, ct ? CS[11] : 0.f, 2); }
      { bool ct = (lane &  2); crx_lane2(sr, si, ct ? CS[12] : 1.f, ct ? CS[13] : 0.f, 1); }
      // --- CRX(7->8): ctrl lane bit0, target reg pair ---
      { bool ct = (lane & 1); crx_reg2(sr, si, ct ? CS[14] : 1.f, ct ? CS[15] : 0.f); }
      // --- CRX(8->0): ctrl r==1, target wv bit1 (cross-wave) ---
      __syncthreads();
      sRe[idx0] = sr[0]; sIm[idx0] = si[0];
      sRe[idx0 + 1] = sr[1]; sIm[idx0 + 1] = si[1];
      __syncthreads();
      {
        float c = CS[16], s = CS[17];
        int p1 = (wv ^ 2) * 128 + lane * 2 + 1;
        float pr = sRe[p1], pi = sIm[p1];
        float nr = c * sr[1] + s * pi;
        float ni = c * si[1] - s * pr;
        sr[1] = nr; si[1] = ni;
      }
    }
#pragma unroll
    for (int r = 0; r < 2; ++r) {
      int j = idx0 + r;
      BT[(size_t)j * DIM + k]         = __float2bfloat16(sr[r]);  // Re W[j,k]
      BT[(size_t)(DIM + j) * DIM + k] = __float2bfloat16(si[r]);  // Im W[j,k]
    }
  } else {
    __shared__ int fx;
    if (tid == 0) fx = looks_bf16(x, B_TOT * DIM);
    __syncthreads();
    size_t i0 = ((size_t)(blockIdx.x - DIM) * 256 + tid) * 8;  // 8 elems/thread
    if (fx) {
      *(uint4*)(A + i0) = *(const uint4*)((const unsigned short*)x + i0);
    } else {
      const float4* src = (const float4*)((const float*)x + i0);
      float4 a = src[0], b = src[1];
      __hip_bfloat16 o[8];
      o[0] = __float2bfloat16(a.x); o[1] = __float2bfloat16(a.y);
      o[2] = __float2bfloat16(a.z); o[3] = __float2bfloat16(a.w);
      o[4] = __float2bfloat16(b.x); o[5] = __float2bfloat16(b.y);
      o[6] = __float2bfloat16(b.z); o[7] = __float2bfloat16(b.w);
      *(uint4*)(A + i0) = *(uint4*)o;
    }
  }
}

// ---------------- GEMM: C = A x BT' (bf16 MFMA), bf16 C output -------------
using frag8 = __attribute__((ext_vector_type(8))) short;
using frag4 = __attribute__((ext_vector_type(4))) float;

typedef __attribute__((address_space(1))) const unsigned int GU32;
typedef __attribute__((address_space(3))) unsigned int LU32;
__device__ __forceinline__ void async16(const void* g, void* l) {
  __builtin_amdgcn_global_load_lds((GU32*)g, (LU32*)l, 16, 0, 0);
}

__global__ __launch_bounds__(256) void gemm_kernel(const unsigned short* __restrict__ A,
                                                   const unsigned short* __restrict__ BT,
                                                   unsigned short* __restrict__ C) {
  __shared__ __align__(16) unsigned short lA[128 * 32];
  __shared__ __align__(16) unsigned short lB[128 * 32];
  int bid = blockIdx.x;
  int xcd = bid & 7;
  int slot = bid >> 3;                       // 0..127
  int n0 = (slot & 7) * 128;                 // n fastest
  int m0 = (xcd * 16 + (slot >> 3)) * 128;   // xcd owns rows [xcd*2048, +2048)
  int tid = threadIdx.x;
  int wv = tid >> 6, lane = tid & 63;
  int wm = wv >> 1, wn = wv & 1;
  int row = lane & 15, quad = lane >> 4;
  int srow = wv * 32 + (lane >> 2);
  int scol = (lane & 3) * 8;
  const unsigned short* gA = A + (size_t)(m0 + srow) * 512 + scol;
  const unsigned short* gB = BT + (size_t)(n0 + srow) * 512 + scol;
  frag4 acc[4][4] = {};
#pragma unroll 1
  for (int k0 = 0; k0 < 512; k0 += 32) {
    __syncthreads();
    async16(gA + k0,            &lA[(wv * 32) * 32]);
    async16(gA + k0 + 16 * 512, &lA[(wv * 32 + 16) * 32]);
    async16(gB + k0,            &lB[(wv * 32) * 32]);
    async16(gB + k0 + 16 * 512, &lB[(wv * 32 + 16) * 32]);
    __syncthreads();
    frag8 af[4], bf[4];
#pragma unroll
    for (int i = 0; i < 4; ++i) {
      af[i] = *(const frag8*)(&lA[(wm * 64 + i * 16 + row) * 32 + quad * 8]);
      bf[i] = *(const frag8*)(&lB[(wn * 64 + i * 16 + row) * 32 + quad * 8]);
    }
#pragma unroll
    for (int mi = 0; mi < 4; ++mi)
#pragma unroll
      for (int ni = 0; ni < 4; ++ni)
        acc[mi][ni] = __builtin_amdgcn_mfma_f32_16x16x32_bf16(af[mi], bf[ni],
                                                              acc[mi][ni], 0, 0, 0);
  }
  // C/D layout: col = lane&15, row = (lane>>4)*4 + reg
#pragma unroll
  for (int mi = 0; mi < 4; ++mi)
#pragma unroll
    for (int ni = 0; ni < 4; ++ni)
#pragma unroll
      for (int rg = 0; rg < 4; ++rg) {
        int m = m0 + wm * 64 + mi * 16 + quad * 4 + rg;
        int n = n0 + wn * 64 + ni * 16 + row;
        __hip_bfloat16 h = __float2bfloat16(acc[mi][ni][rg]);
        C[(size_t)m * 1024 + n] = *(unsigned short*)&h;
      }
}

// ---------------- epilogue: probs -> z -> logits -> log_softmax ------------
__global__ __launch_bounds__(256) void epi_kernel(const unsigned short* __restrict__ C,
                                                  const void* __restrict__ fcw,
                                                  const void* __restrict__ fcb,
                                                  float* __restrict__ out) {
  __shared__ int flags[2];
  int tid = threadIdx.x;
  if (tid == 0) {
    flags[0] = looks_bf16(fcw, NCLS * NQ);
    flags[1] = looks_bf16(fcb, NCLS);
  }
  __syncthreads();
  int b = (blockIdx.x * 256 + tid) >> 6;
  int lane = tid & 63;
  const unsigned short* rowp = C + (size_t)b * 1024;
  const uint4 ur = *(const uint4*)(rowp + lane * 8);
  const uint4 ui = *(const uint4*)(rowp + 512 + lane * 8);
  float cr[8], ci[8];
  cr[0] = __uint_as_float(ur.x << 16); cr[1] = __uint_as_float(ur.x & 0xffff0000u);
  cr[2] = __uint_as_float(ur.y << 16); cr[3] = __uint_as_float(ur.y & 0xffff0000u);
  cr[4] = __uint_as_float(ur.z << 16); cr[5] = __uint_as_float(ur.z & 0xffff0000u);
  cr[6] = __uint_as_float(ur.w << 16); cr[7] = __uint_as_float(ur.w & 0xffff0000u);
  ci[0] = __uint_as_float(ui.x << 16); ci[1] = __uint_as_float(ui.x & 0xffff0000u);
  ci[2] = __uint_as_float(ui.y << 16); ci[3] = __uint_as_float(ui.y & 0xffff0000u);
  ci[4] = __uint_as_float(ui.z << 16); ci[5] = __uint_as_float(ui.z & 0xffff0000u);
  ci[6] = __uint_as_float(ui.w << 16); ci[7] = __uint_as_float(ui.w & 0xffff0000u);
  float p[8], P = 0.f;
#pragma unroll
  for (int r = 0; r < 8; ++r) { p[r] = cr[r] * cr[r] + ci[r] * ci[r]; P += p[r]; }
  float z[NQ + 1];
#pragma unroll
  for (int q = 0; q < 6; ++q) z[q] = (lane & (32 >> q)) ? -P : P;
  z[6] = z[7] = z[8] = 0.f;
#pragma unroll
  for (int r = 0; r < 8; ++r) {
    z[6] += (r & 4) ? -p[r] : p[r];
    z[7] += (r & 2) ? -p[r] : p[r];
    z[8] += (r & 1) ? -p[r] : p[r];
  }
  z[9] = P;  // total norm^2 (unitary preserves norm; input unnormalized)
#pragma unroll
  for (int m = 1; m < 64; m <<= 1) {
#pragma unroll
    for (int q = 0; q < NQ + 1; ++q) z[q] += shx(z[q], m);
  }
  float invP = 1.0f / z[9];
#pragma unroll
  for (int q = 0; q < NQ; ++q) z[q] *= invP;
  int ffw = flags[0], ffb = flags[1];
  float lg[NCLS], mx = -1e30f;
#pragma unroll
  for (int k = 0; k < NCLS; ++k) {
    float t = ld(fcb, k, ffb);
#pragma unroll
    for (int q = 0; q < NQ; ++q) t += z[q] * ld(fcw, k * NQ + q, ffw);
    lg[k] = t; mx = fmaxf(mx, t);
  }
  float se = 0.f;
#pragma unroll
  for (int k = 0; k < NCLS; ++k) se += expf(lg[k] - mx);
  float lse = mx + logf(se);
  if (lane < NCLS) out[(size_t)b * NCLS + lane] = lg[lane] - lse;
}

// ---------------- fallback: round-3 passing monolithic kernel --------------
__global__ __launch_bounds__(256) void qnn_kernel(
    const void* __restrict__ x, const void* __restrict__ rot,
    const void* __restrict__ crx, const void* __restrict__ fcw,
    const void* __restrict__ fcb, float* __restrict__ out) {
  __shared__ __align__(16) float gU[NL * NQ * 8];
  __shared__ __align__(16) float gCS[NL * NQ * 2];
  __shared__ int flags[3];
  int tid = threadIdx.x;
  if (tid == 0) {
    flags[0] = looks_bf16(x, B_TOT * DIM);
    flags[1] = looks_bf16(fcw, NCLS * NQ);
    flags[2] = looks_bf16(fcb, NCLS);
  }
  build_gates(rot, crx, gU, gCS);
  __syncthreads();
  int wid = (blockIdx.x * blockDim.x + tid) >> 6;
  int lane = tid & 63;
  float sr[8], si[8];
  if (flags[0]) {
    const uint4 u = *(const uint4*)((const unsigned short*)x + (size_t)wid * DIM + lane * 8);
    sr[0] = __uint_as_float(u.x << 16); sr[1] = __uint_as_float(u.x & 0xffff0000u);
    sr[2] = __uint_as_float(u.y << 16); sr[3] = __uint_as_float(u.y & 0xffff0000u);
    sr[4] = __uint_as_float(u.z << 16); sr[5] = __uint_as_float(u.z & 0xffff0000u);
    sr[6] = __uint_as_float(u.w << 16); sr[7] = __uint_as_float(u.w & 0xffff0000u);
  } else {
    const float4* xf = (const float4*)((const float*)x + (size_t)wid * DIM) + lane * 2;
    float4 a = xf[0], b = xf[1];
    sr[0] = a.x; sr[1] = a.y; sr[2] = a.z; sr[3] = a.w;
    sr[4] = b.x; sr[5] = b.y; sr[6] = b.z; sr[7] = b.w;
  }
  float nrm = 0.f;
#pragma unroll
  for (int r = 0; r < 8; ++r) { nrm += sr[r] * sr[r]; si[r] = 0.f; }
#pragma unroll
  for (int m = 1; m < 64; m <<= 1) nrm += shx(nrm, m);
  float inv = rsqrtf(nrm);
  inv = inv * (1.5f - 0.5f * nrm * inv * inv);
#pragma unroll
  for (int r = 0; r < 8; ++r) sr[r] *= inv;
  run_circuit(sr, si, gU, gCS);
  float p[8], P = 0.f;
#pragma unroll
  for (int r = 0; r < 8; ++r) { p[r] = sr[r] * sr[r] + si[r] * si[r]; P += p[r]; }
  float z[NQ];
#pragma unroll
  for (int q = 0; q < 6; ++q) z[q] = (lane & (32 >> q)) ? -P : P;
  z[6] = z[7] = z[8] = 0.f;
#pragma unroll
  for (int r = 0; r < 8; ++r) {
    z[6] += (r & 4) ? -p[r] : p[r];
    z[7] += (r & 2) ? -p[r] : p[r];
    z[8] += (r & 1) ? -p[r] : p[r];
  }
#pragma unroll
  for (int m = 1; m < 64; m <<= 1) {
#pragma unroll
    for (int q = 0; q < NQ; ++q) z[q] += shx(z[q], m);
  }
  int ffw = flags[1], ffb = flags[2];
  float lg[NCLS], mx = -1e30f;
#pragma unroll
  for (int k = 0; k < NCLS; ++k) {
    float t = ld(fcb, k, ffb);
#pragma unroll
    for (int q = 0; q < NQ; ++q) t += z[q] * ld(fcw, k * NQ + q, ffw);
    lg[k] = t; mx = fmaxf(mx, t);
  }
  float se = 0.f;
#pragma unroll
  for (int k = 0; k < NCLS; ++k) se += expf(lg[k] - mx);
  float lse = mx + logf(se);
  if (lane < NCLS) out[(size_t)wid * NCLS + lane] = lg[lane] - lse;
}

extern "C" void kernel_launch(void* const* d_in, const int* in_sizes, int n_in,
                              void* d_out, int out_size, void* d_ws, size_t ws_size,
                              hipStream_t stream) {
  const void* x   = d_in[0];
  const void* rot = d_in[1];
  const void* crx = d_in[2];
  const void* fcw = d_in[3];
  const void* fcb = d_in[4];
  float* out = (float*)d_out;
  if (ws_size >= WS_NEED) {
    __hip_bfloat16* A  = (__hip_bfloat16*)((char*)d_ws + A_OFF);
    __hip_bfloat16* BT = (__hip_bfloat16*)((char*)d_ws + BT_OFF);
    unsigned short* C  = (unsigned short*)((char*)d_ws + C_OFF);
    // 512 wbuild blocks (1 column each, 4 waves) + 4096 cast blocks
    prep_kernel<<<DIM + (B_TOT * DIM) / (256 * 8), 256, 0, stream>>>(x, rot, crx, A, BT);
    gemm_kernel<<<(B_TOT / 128) * (1024 / 128), 256, 0, stream>>>(
        (const unsigned short*)A, (const unsigned short*)BT, C);
    epi_kernel<<<(B_TOT * 64) / 256, 256, 0, stream>>>(C, fcw, fcb, out);
  } else {
    qnn_kernel<<<(B_TOT * 64) / 256, 256, 0, stream>>>(x, rot, crx, fcw, fcb, out);
  }
}

// Round 8
// 165.158 us; speedup vs baseline: 2.9799x; 1.0861x over previous
//
#include <hip/hip_runtime.h>
#include <hip/hip_bf16.h>
#include <math.h>

#define NQ 9
#define NL 10
#define DIM 512
#define NCLS 10
#define B_TOT 16384

// ws layout (bytes): A bf16 [16384x512] @ 0 (16MB); BT bf16 [1024x512] @ 16MB (1MB);
// C bf16 [16384x1024] @ 32MB (32MB).
#define A_OFF   ((size_t)0)
#define BT_OFF  ((size_t)16 << 20)
#define C_OFF   ((size_t)32 << 20)
#define WS_NEED (((size_t)96) << 20)

__device__ __forceinline__ float shx(float v, int m) { return __shfl_xor(v, m, 64); }

__device__ __forceinline__ int looks_bf16(const void* p, int count) {
  const unsigned short* u = (const unsigned short*)p;
  int n = count < 64 ? count : 64;
  int good = 0;
  for (int i = 0; i < n; ++i) {
    unsigned short v = u[i];
    int e = (v >> 7) & 0xFF;
    good += (e >= 100 && e <= 140) || ((v & 0x7FFF) == 0);
  }
  return good * 8 >= n * 7;
}

__device__ __forceinline__ float ld(const void* p, int i, int isbf) {
  if (isbf) return __uint_as_float(((unsigned)((const unsigned short*)p)[i]) << 16);
  return ((const float*)p)[i];
}

// ---------------- 8-amp gate helpers (verified R3; used by fallback) -------
template<int M>
__device__ __forceinline__ void rot_x(float (&sr)[8], float (&si)[8], const float* u) {
  float4 uA = *(const float4*)u;
  float4 uB = *(const float4*)(u + 4);
  bool hi = (threadIdx.x & M) != 0;
  float ar = hi ? uB.z : uA.x, ai = hi ? uB.w : uA.y;
  float br = hi ? uB.x : uA.z, bi = hi ? uB.y : uA.w;
#pragma unroll
  for (int r = 0; r < 8; ++r) {
    float pr = shx(sr[r], M), pi = shx(si[r], M);
    float nr = ar * sr[r] - ai * si[r] + br * pr - bi * pi;
    float ni = ar * si[r] + ai * sr[r] + br * pi + bi * pr;
    sr[r] = nr; si[r] = ni;
  }
}
template<int S>
__device__ __forceinline__ void rot_r(float (&sr)[8], float (&si)[8], const float* u) {
  float4 uA = *(const float4*)u;
  float4 uB = *(const float4*)(u + 4);
#pragma unroll
  for (int r0 = 0; r0 < 8; ++r0) {
    if (r0 & S) continue;
    int r1 = r0 + S;
    float a0r = sr[r0], a0i = si[r0], a1r = sr[r1], a1i = si[r1];
    sr[r0] = uA.x * a0r - uA.y * a0i + uA.z * a1r - uA.w * a1i;
    si[r0] = uA.x * a0i + uA.y * a0r + uA.z * a1i + uA.w * a1r;
    sr[r1] = uB.x * a0r - uB.y * a0i + uB.z * a1r - uB.w * a1i;
    si[r1] = uB.x * a0i + uB.y * a0r + uB.z * a1i + uB.w * a1r;
  }
}
template<int MC, int MT>
__device__ __forceinline__ void crx_ll(float (&sr)[8], float (&si)[8], const float* cs) {
  bool ctrl = (threadIdx.x & MC) != 0;
  float c = ctrl ? cs[0] : 1.0f;
  float s = ctrl ? cs[1] : 0.0f;
#pragma unroll
  for (int r = 0; r < 8; ++r) {
    float pr = shx(sr[r], MT), pi = shx(si[r], MT);
    float nr = c * sr[r] + s * pi;
    float ni = c * si[r] - s * pr;
    sr[r] = nr; si[r] = ni;
  }
}
template<int MC, int ST>
__device__ __forceinline__ void crx_lr(float (&sr)[8], float (&si)[8], const float* cs) {
  bool ctrl = (threadIdx.x & MC) != 0;
  float c = ctrl ? cs[0] : 1.0f;
  float s = ctrl ? cs[1] : 0.0f;
#pragma unroll
  for (int r0 = 0; r0 < 8; ++r0) {
    if (r0 & ST) continue;
    int r1 = r0 + ST;
    float a0r = sr[r0], a0i = si[r0], a1r = sr[r1], a1i = si[r1];
    sr[r0] = c * a0r + s * a1i;  si[r0] = c * a0i - s * a1r;
    sr[r1] = c * a1r + s * a0i;  si[r1] = c * a1i - s * a0r;
  }
}
template<int PC, int ST>
__device__ __forceinline__ void crx_rr(float (&sr)[8], float (&si)[8], const float* cs) {
  float c = cs[0], s = cs[1];
#pragma unroll
  for (int r0 = 0; r0 < 8; ++r0) {
    if (r0 & ST) continue;
    if (!((r0 >> PC) & 1)) continue;
    int r1 = r0 + ST;
    float a0r = sr[r0], a0i = si[r0], a1r = sr[r1], a1i = si[r1];
    sr[r0] = c * a0r + s * a1i;  si[r0] = c * a0i - s * a1r;
    sr[r1] = c * a1r + s * a0i;  si[r1] = c * a1i - s * a0r;
  }
}
template<int PC, int MT>
__device__ __forceinline__ void crx_rl(float (&sr)[8], float (&si)[8], const float* cs) {
  float c = cs[0], s = cs[1];
#pragma unroll
  for (int r = 0; r < 8; ++r) {
    if (!((r >> PC) & 1)) continue;
    float pr = shx(sr[r], MT), pi = shx(si[r], MT);
    float nr = c * sr[r] + s * pi;
    float ni = c * si[r] - s * pr;
    sr[r] = nr; si[r] = ni;
  }
}

__device__ __forceinline__ void build_gates(const void* rot, const void* crx,
                                            float* gU, float* gCS) {
  int tid = threadIdx.x;
  __shared__ int gflags[2];
  if (tid == 0) {
    gflags[0] = looks_bf16(rot, NL * NQ * 3);
    gflags[1] = looks_bf16(crx, NL * NQ);
  }
  __syncthreads();
  if (tid < NL * NQ) {
    int frot = gflags[0], fcrx = gflags[1];
    float phi = ld(rot, tid * 3 + 0, frot);
    float th  = ld(rot, tid * 3 + 1, frot);
    float om  = ld(rot, tid * 3 + 2, frot);
    float c = cosf(0.5f * th), s = sinf(0.5f * th);
    float a = 0.5f * (phi + om), b = 0.5f * (phi - om);
    float ca = cosf(a), sa = sinf(a), cb = cosf(b), sb = sinf(b);
    float* u = gU + tid * 8;
    u[0] =  ca * c; u[1] = -sa * c;
    u[2] = -cb * s; u[3] = -sb * s;
    u[4] =  cb * s; u[5] = -sb * s;
    u[6] =  ca * c; u[7] =  sa * c;
    float t2 = 0.5f * ld(crx, tid, fcrx);
    gCS[tid * 2 + 0] = cosf(t2);
    gCS[tid * 2 + 1] = sinf(t2);
  }
  __syncthreads();
}

__device__ __forceinline__ void run_circuit(float (&sr)[8], float (&si)[8],
                                            const float* gU, const float* gCS) {
#pragma unroll 1
  for (int n = 0; n < NL; ++n) {
    const float* U  = gU  + n * NQ * 8;
    const float* CS = gCS + n * NQ * 2;
    rot_x<32>(sr, si, U + 0 * 8);
    rot_x<16>(sr, si, U + 1 * 8);
    rot_x< 8>(sr, si, U + 2 * 8);
    rot_x< 4>(sr, si, U + 3 * 8);
    rot_x< 2>(sr, si, U + 4 * 8);
    rot_x< 1>(sr, si, U + 5 * 8);
    rot_r< 4>(sr, si, U + 6 * 8);
    rot_r< 2>(sr, si, U + 7 * 8);
    rot_r< 1>(sr, si, U + 8 * 8);
    crx_ll<32, 16>(sr, si, CS + 0 * 2);
    crx_ll<16,  8>(sr, si, CS + 1 * 2);
    crx_ll< 8,  4>(sr, si, CS + 2 * 2);
    crx_ll< 4,  2>(sr, si, CS + 3 * 2);
    crx_ll< 2,  1>(sr, si, CS + 4 * 2);
    crx_lr< 1,  4>(sr, si, CS + 5 * 2);
    crx_rr< 2,  2>(sr, si, CS + 6 * 2);
    crx_rr< 1,  1>(sr, si, CS + 7 * 2);
    crx_rl< 0, 32>(sr, si, CS + 8 * 2);
  }
}

// ---------------- 2-amp gate helpers (4-wave-per-column wbuild) ------------
template<int M>
__device__ __forceinline__ void rot_lane2(float (&sr)[2], float (&si)[2], const float* u) {
  float4 uA = *(const float4*)u;
  float4 uB = *(const float4*)(u + 4);
  bool hi = (threadIdx.x & M) != 0;
  float ar = hi ? uB.z : uA.x, ai = hi ? uB.w : uA.y;
  float br = hi ? uB.x : uA.z, bi = hi ? uB.y : uA.w;
#pragma unroll
  for (int r = 0; r < 2; ++r) {
    float pr = shx(sr[r], M), pi = shx(si[r], M);
    float nr = ar * sr[r] - ai * si[r] + br * pr - bi * pi;
    float ni = ar * si[r] + ai * sr[r] + br * pi + bi * pr;
    sr[r] = nr; si[r] = ni;
  }
}
__device__ __forceinline__ void rot_reg2(float (&sr)[2], float (&si)[2], const float* u) {
  float4 uA = *(const float4*)u;
  float4 uB = *(const float4*)(u + 4);
  float a0r = sr[0], a0i = si[0], a1r = sr[1], a1i = si[1];
  sr[0] = uA.x * a0r - uA.y * a0i + uA.z * a1r - uA.w * a1i;
  si[0] = uA.x * a0i + uA.y * a0r + uA.z * a1i + uA.w * a1r;
  sr[1] = uB.x * a0r - uB.y * a0i + uB.z * a1r - uB.w * a1i;
  si[1] = uB.x * a0i + uB.y * a0r + uB.z * a1i + uB.w * a1r;
}
__device__ __forceinline__ void crx_lane2(float (&sr)[2], float (&si)[2],
                                          float c, float s, int MT) {
#pragma unroll
  for (int r = 0; r < 2; ++r) {
    float pr = shx(sr[r], MT), pi = shx(si[r], MT);
    float nr = c * sr[r] + s * pi;
    float ni = c * si[r] - s * pr;
    sr[r] = nr; si[r] = ni;
  }
}
__device__ __forceinline__ void crx_reg2(float (&sr)[2], float (&si)[2], float c, float s) {
  float a0r = sr[0], a0i = si[0], a1r = sr[1], a1i = si[1];
  sr[0] = c * a0r + s * a1i;  si[0] = c * a0i - s * a1r;
  sr[1] = c * a1r + s * a0i;  si[1] = c * a1i - s * a0r;
}

// -------- fused prep: blocks 0..511 build one W column each (4 waves/col),
// -------- blocks 512.. cast x->bf16 and fill remaining SIMDs ---------------
__global__ __launch_bounds__(256) void prep_kernel(const void* __restrict__ x,
                                                   const void* __restrict__ rot,
                                                   const void* __restrict__ crx,
                                                   __hip_bfloat16* __restrict__ A,
                                                   __hip_bfloat16* __restrict__ BT) {
  int tid = threadIdx.x;
  if (blockIdx.x < DIM) {
    __shared__ __align__(16) float gU[NL * NQ * 8];
    __shared__ __align__(16) float gCS[NL * NQ * 2];
    __shared__ float sRe[DIM], sIm[DIM];
    build_gates(rot, crx, gU, gCS);
    int lane = tid & 63, wv = tid >> 6;
    int idx0 = wv * 128 + lane * 2;
    int k = blockIdx.x;
    float sr[2], si[2];
    sr[0] = (idx0 == k) ? 1.f : 0.f;
    sr[1] = (idx0 + 1 == k) ? 1.f : 0.f;
    si[0] = si[1] = 0.f;
#pragma unroll 1
    for (int n = 0; n < NL; ++n) {
      const float* U  = gU  + n * NQ * 8;
      const float* CS = gCS + n * NQ * 2;
      __syncthreads();
      sRe[idx0] = sr[0]; sIm[idx0] = si[0];
      sRe[idx0 + 1] = sr[1]; sIm[idx0 + 1] = si[1];
      __syncthreads();
      {
        const float* U0 = U; const float* U1 = U + 8;
        int a = wv >> 1, b = wv & 1;
        float mr[4], mi[4];
#pragma unroll
        for (int w2 = 0; w2 < 4; ++w2) {
          int a2 = w2 >> 1, b2 = w2 & 1;
          float u0r = U0[(a * 2 + a2) * 2], u0i = U0[(a * 2 + a2) * 2 + 1];
          float u1r = U1[(b * 2 + b2) * 2], u1i = U1[(b * 2 + b2) * 2 + 1];
          mr[w2] = u0r * u1r - u0i * u1i;
          mi[w2] = u0r * u1i + u0i * u1r;
        }
#pragma unroll
        for (int r = 0; r < 2; ++r) {
          float nr = 0.f, ni = 0.f;
#pragma unroll
          for (int w2 = 0; w2 < 4; ++w2) {
            float xr = sRe[w2 * 128 + lane * 2 + r];
            float xi = sIm[w2 * 128 + lane * 2 + r];
            nr += mr[w2] * xr - mi[w2] * xi;
            ni += mr[w2] * xi + mi[w2] * xr;
          }
          sr[r] = nr; si[r] = ni;
        }
      }
      rot_lane2<32>(sr, si, U + 2 * 8);
      rot_lane2<16>(sr, si, U + 3 * 8);
      rot_lane2< 8>(sr, si, U + 4 * 8);
      rot_lane2< 4>(sr, si, U + 5 * 8);
      rot_lane2< 2>(sr, si, U + 6 * 8);
      rot_lane2< 1>(sr, si, U + 7 * 8);
      rot_reg2(sr, si, U + 8 * 8);
      __syncthreads();
      sRe[idx0] = sr[0]; sIm[idx0] = si[0];
      sRe[idx0 + 1] = sr[1]; sIm[idx0 + 1] = si[1];
      __syncthreads();
      {
        float c = (wv & 2) ? CS[0] : 1.f, s = (wv & 2) ? CS[1] : 0.f;
        int p0 = (wv ^ 1) * 128 + lane * 2;
#pragma unroll
        for (int r = 0; r < 2; ++r) {
          float pr = sRe[p0 + r], pi = sIm[p0 + r];
          float nr = c * sr[r] + s * pi;
          float ni = c * si[r] - s * pr;
          sr[r] = nr; si[r] = ni;
        }
      }
      { float c = (wv & 1) ? CS[2] : 1.f, s = (wv & 1) ? CS[3] : 0.f;
        crx_lane2(sr, si, c, s, 32); }
      { bool ct = (lane & 32); crx_lane2(sr, si, ct ? CS[4] : 1.f, ct ? CS[5] : 0.f, 16); }
      { bool ct = (lane & 16); crx_lane2(sr, si, ct ? CS[6] : 1.f, ct ? CS[7] : 0.f, 8); }
      { bool ct = (lane &  8); crx_lane2(sr, si, ct ? CS[8] : 1.f, ct ? CS[9] : 0.f, 4); }
      { bool ct = (lane &  4); crx_lane2(sr, si, ct ? CS[10] : 1.f, ct ? CS[11] : 0.f, 2); }
      { bool ct = (lane &  2); crx_lane2(sr, si, ct ? CS[12] : 1.f, ct ? CS[13] : 0.f, 1); }
      { bool ct = (lane & 1); crx_reg2(sr, si, ct ? CS[14] : 1.f, ct ? CS[15] : 0.f); }
      __syncthreads();
      sRe[idx0] = sr[0]; sIm[idx0] = si[0];
      sRe[idx0 + 1] = sr[1]; sIm[idx0 + 1] = si[1];
      __syncthreads();
      {
        float c = CS[16], s = CS[17];
        int p1 = (wv ^ 2) * 128 + lane * 2 + 1;
        float pr = sRe[p1], pi = sIm[p1];
        float nr = c * sr[1] + s * pi;
        float ni = c * si[1] - s * pr;
        sr[1] = nr; si[1] = ni;
      }
    }
#pragma unroll
    for (int r = 0; r < 2; ++r) {
      int j = idx0 + r;
      BT[(size_t)j * DIM + k]         = __float2bfloat16(sr[r]);  // Re W[j,k]
      BT[(size_t)(DIM + j) * DIM + k] = __float2bfloat16(si[r]);  // Im W[j,k]
    }
  } else {
    __shared__ int fx;
    if (tid == 0) fx = looks_bf16(x, B_TOT * DIM);
    __syncthreads();
    size_t i0 = ((size_t)(blockIdx.x - DIM) * 256 + tid) * 8;
    if (fx) {
      *(uint4*)(A + i0) = *(const uint4*)((const unsigned short*)x + i0);
    } else {
      const float4* src = (const float4*)((const float*)x + i0);
      float4 a = src[0], b = src[1];
      __hip_bfloat16 o[8];
      o[0] = __float2bfloat16(a.x); o[1] = __float2bfloat16(a.y);
      o[2] = __float2bfloat16(a.z); o[3] = __float2bfloat16(a.w);
      o[4] = __float2bfloat16(b.x); o[5] = __float2bfloat16(b.y);
      o[6] = __float2bfloat16(b.z); o[7] = __float2bfloat16(b.w);
      *(uint4*)(A + i0) = *(uint4*)o;
    }
  }
}

// ---------------- GEMM: C = A x BT' (bf16 MFMA), bf16 C output -------------
using frag8 = __attribute__((ext_vector_type(8))) short;
using frag4 = __attribute__((ext_vector_type(4))) float;

typedef __attribute__((address_space(1))) const unsigned int GU32;
typedef __attribute__((address_space(3))) unsigned int LU32;
__device__ __forceinline__ void async16(const void* g, void* l) {
  __builtin_amdgcn_global_load_lds((GU32*)g, (LU32*)l, 16, 0, 0);
}

__global__ __launch_bounds__(256) void gemm_kernel(const unsigned short* __restrict__ A,
                                                   const unsigned short* __restrict__ BT,
                                                   unsigned short* __restrict__ C) {
  __shared__ __align__(16) unsigned short lA[128 * 32];
  __shared__ __align__(16) unsigned short lB[128 * 32];
  int bid = blockIdx.x;
  int xcd = bid & 7;
  int slot = bid >> 3;
  int n0 = (slot & 7) * 128;
  int m0 = (xcd * 16 + (slot >> 3)) * 128;
  int tid = threadIdx.x;
  int wv = tid >> 6, lane = tid & 63;
  int wm = wv >> 1, wn = wv & 1;
  int row = lane & 15, quad = lane >> 4;
  int srow = wv * 32 + (lane >> 2);
  int scol = (lane & 3) * 8;
  const unsigned short* gA = A + (size_t)(m0 + srow) * 512 + scol;
  const unsigned short* gB = BT + (size_t)(n0 + srow) * 512 + scol;
  frag4 acc[4][4] = {};
#pragma unroll 1
  for (int k0 = 0; k0 < 512; k0 += 32) {
    __syncthreads();
    async16(gA + k0,            &lA[(wv * 32) * 32]);
    async16(gA + k0 + 16 * 512, &lA[(wv * 32 + 16) * 32]);
    async16(gB + k0,            &lB[(wv * 32) * 32]);
    async16(gB + k0 + 16 * 512, &lB[(wv * 32 + 16) * 32]);
    __syncthreads();
    frag8 af[4], bf[4];
#pragma unroll
    for (int i = 0; i < 4; ++i) {
      af[i] = *(const frag8*)(&lA[(wm * 64 + i * 16 + row) * 32 + quad * 8]);
      bf[i] = *(const frag8*)(&lB[(wn * 64 + i * 16 + row) * 32 + quad * 8]);
    }
#pragma unroll
    for (int mi = 0; mi < 4; ++mi)
#pragma unroll
      for (int ni = 0; ni < 4; ++ni)
        acc[mi][ni] = __builtin_amdgcn_mfma_f32_16x16x32_bf16(af[mi], bf[ni],
                                                              acc[mi][ni], 0, 0, 0);
  }
#pragma unroll
  for (int mi = 0; mi < 4; ++mi)
#pragma unroll
    for (int ni = 0; ni < 4; ++ni)
#pragma unroll
      for (int rg = 0; rg < 4; ++rg) {
        int m = m0 + wm * 64 + mi * 16 + quad * 4 + rg;
        int n = n0 + wn * 64 + ni * 16 + row;
        __hip_bfloat16 h = __float2bfloat16(acc[mi][ni][rg]);
        C[(size_t)m * 1024 + n] = *(unsigned short*)&h;
      }
}

// ---------------- epilogue: probs -> z -> logits -> log_softmax ------------
// fcw/fcb staged in LDS as f32: kills the 90 serialized per-lane global
// scalar loads that made epi latency-bound (46 us, VALUBusy 31%).
__global__ __launch_bounds__(256) void epi_kernel(const unsigned short* __restrict__ C,
                                                  const void* __restrict__ fcw,
                                                  const void* __restrict__ fcb,
                                                  float* __restrict__ out) {
  __shared__ int flags[2];
  __shared__ float sW[NCLS * NQ];
  __shared__ float sB[NCLS];
  int tid = threadIdx.x;
  if (tid == 0) {
    flags[0] = looks_bf16(fcw, NCLS * NQ);
    flags[1] = looks_bf16(fcb, NCLS);
  }
  __syncthreads();
  if (tid < NCLS * NQ) sW[tid] = ld(fcw, tid, flags[0]);
  if (tid < NCLS)      sB[tid] = ld(fcb, tid, flags[1]);
  __syncthreads();
  int b = (blockIdx.x * 256 + tid) >> 6;
  int lane = tid & 63;
  const unsigned short* rowp = C + (size_t)b * 1024;
  const uint4 ur = *(const uint4*)(rowp + lane * 8);
  const uint4 ui = *(const uint4*)(rowp + 512 + lane * 8);
  float cr[8], ci[8];
  cr[0] = __uint_as_float(ur.x << 16); cr[1] = __uint_as_float(ur.x & 0xffff0000u);
  cr[2] = __uint_as_float(ur.y << 16); cr[3] = __uint_as_float(ur.y & 0xffff0000u);
  cr[4] = __uint_as_float(ur.z << 16); cr[5] = __uint_as_float(ur.z & 0xffff0000u);
  cr[6] = __uint_as_float(ur.w << 16); cr[7] = __uint_as_float(ur.w & 0xffff0000u);
  ci[0] = __uint_as_float(ui.x << 16); ci[1] = __uint_as_float(ui.x & 0xffff0000u);
  ci[2] = __uint_as_float(ui.y << 16); ci[3] = __uint_as_float(ui.y & 0xffff0000u);
  ci[4] = __uint_as_float(ui.z << 16); ci[5] = __uint_as_float(ui.z & 0xffff0000u);
  ci[6] = __uint_as_float(ui.w << 16); ci[7] = __uint_as_float(ui.w & 0xffff0000u);
  float p[8], P = 0.f;
#pragma unroll
  for (int r = 0; r < 8; ++r) { p[r] = cr[r] * cr[r] + ci[r] * ci[r]; P += p[r]; }
  float z[NQ + 1];
#pragma unroll
  for (int q = 0; q < 6; ++q) z[q] = (lane & (32 >> q)) ? -P : P;
  z[6] = z[7] = z[8] = 0.f;
#pragma unroll
  for (int r = 0; r < 8; ++r) {
    z[6] += (r & 4) ? -p[r] : p[r];
    z[7] += (r & 2) ? -p[r] : p[r];
    z[8] += (r & 1) ? -p[r] : p[r];
  }
  z[9] = P;  // total norm^2 (unitary preserves norm; input unnormalized)
#pragma unroll
  for (int m = 1; m < 64; m <<= 1) {
#pragma unroll
    for (int q = 0; q < NQ + 1; ++q) z[q] += shx(z[q], m);
  }
  float invP = 1.0f / z[9];
#pragma unroll
  for (int q = 0; q < NQ; ++q) z[q] *= invP;
  float lg[NCLS], mx = -1e30f;
#pragma unroll
  for (int k = 0; k < NCLS; ++k) {
    float t = sB[k];
#pragma unroll
    for (int q = 0; q < NQ; ++q) t += z[q] * sW[k * NQ + q];
    lg[k] = t; mx = fmaxf(mx, t);
  }
  float se = 0.f;
#pragma unroll
  for (int k = 0; k < NCLS; ++k) se += expf(lg[k] - mx);
  float lse = mx + logf(se);
  if (lane < NCLS) out[(size_t)b * NCLS + lane] = lg[lane] - lse;
}

// ---------------- fallback: round-3 passing monolithic kernel --------------
__global__ __launch_bounds__(256) void qnn_kernel(
    const void* __restrict__ x, const void* __restrict__ rot,
    const void* __restrict__ crx, const void* __restrict__ fcw,
    const void* __restrict__ fcb, float* __restrict__ out) {
  __shared__ __align__(16) float gU[NL * NQ * 8];
  __shared__ __align__(16) float gCS[NL * NQ * 2];
  __shared__ int flags[3];
  int tid = threadIdx.x;
  if (tid == 0) {
    flags[0] = looks_bf16(x, B_TOT * DIM);
    flags[1] = looks_bf16(fcw, NCLS * NQ);
    flags[2] = looks_bf16(fcb, NCLS);
  }
  build_gates(rot, crx, gU, gCS);
  __syncthreads();
  int wid = (blockIdx.x * blockDim.x + tid) >> 6;
  int lane = tid & 63;
  float sr[8], si[8];
  if (flags[0]) {
    const uint4 u = *(const uint4*)((const unsigned short*)x + (size_t)wid * DIM + lane * 8);
    sr[0] = __uint_as_float(u.x << 16); sr[1] = __uint_as_float(u.x & 0xffff0000u);
    sr[2] = __uint_as_float(u.y << 16); sr[3] = __uint_as_float(u.y & 0xffff0000u);
    sr[4] = __uint_as_float(u.z << 16); sr[5] = __uint_as_float(u.z & 0xffff0000u);
    sr[6] = __uint_as_float(u.w << 16); sr[7] = __uint_as_float(u.w & 0xffff0000u);
  } else {
    const float4* xf = (const float4*)((const float*)x + (size_t)wid * DIM) + lane * 2;
    float4 a = xf[0], b = xf[1];
    sr[0] = a.x; sr[1] = a.y; sr[2] = a.z; sr[3] = a.w;
    sr[4] = b.x; sr[5] = b.y; sr[6] = b.z; sr[7] = b.w;
  }
  float nrm = 0.f;
#pragma unroll
  for (int r = 0; r < 8; ++r) { nrm += sr[r] * sr[r]; si[r] = 0.f; }
#pragma unroll
  for (int m = 1; m < 64; m <<= 1) nrm += shx(nrm, m);
  float inv = rsqrtf(nrm);
  inv = inv * (1.5f - 0.5f * nrm * inv * inv);
#pragma unroll
  for (int r = 0; r < 8; ++r) sr[r] *= inv;
  run_circuit(sr, si, gU, gCS);
  float p[8], P = 0.f;
#pragma unroll
  for (int r = 0; r < 8; ++r) { p[r] = sr[r] * sr[r] + si[r] * si[r]; P += p[r]; }
  float z[NQ];
#pragma unroll
  for (int q = 0; q < 6; ++q) z[q] = (lane & (32 >> q)) ? -P : P;
  z[6] = z[7] = z[8] = 0.f;
#pragma unroll
  for (int r = 0; r < 8; ++r) {
    z[6] += (r & 4) ? -p[r] : p[r];
    z[7] += (r & 2) ? -p[r] : p[r];
    z[8] += (r & 1) ? -p[r] : p[r];
  }
#pragma unroll
  for (int m = 1; m < 64; m <<= 1) {
#pragma unroll
    for (int q = 0; q < NQ; ++q) z[q] += shx(z[q], m);
  }
  int ffw = flags[1], ffb = flags[2];
  float lg[NCLS], mx = -1e30f;
#pragma unroll
  for (int k = 0; k < NCLS; ++k) {
    float t = ld(fcb, k, ffb);
#pragma unroll
    for (int q = 0; q < NQ; ++q) t += z[q] * ld(fcw, k * NQ + q, ffw);
    lg[k] = t; mx = fmaxf(mx, t);
  }
  float se = 0.f;
#pragma unroll
  for (int k = 0; k < NCLS; ++k) se += expf(lg[k] - mx);
  float lse = mx + logf(se);
  if (lane < NCLS) out[(size_t)wid * NCLS + lane] = lg[lane] - lse;
}

extern "C" void kernel_launch(void* const* d_in, const int* in_sizes, int n_in,
                              void* d_out, int out_size, void* d_ws, size_t ws_size,
                              hipStream_t stream) {
  const void* x   = d_in[0];
  const void* rot = d_in[1];
  const void* crx = d_in[2];
  const void* fcw = d_in[3];
  const void* fcb = d_in[4];
  float* out = (float*)d_out;
  if (ws_size >= WS_NEED) {
    __hip_bfloat16* A  = (__hip_bfloat16*)((char*)d_ws + A_OFF);
    __hip_bfloat16* BT = (__hip_bfloat16*)((char*)d_ws + BT_OFF);
    unsigned short* C  = (unsigned short*)((char*)d_ws + C_OFF);
    prep_kernel<<<DIM + (B_TOT * DIM) / (256 * 8), 256, 0, stream>>>(x, rot, crx, A, BT);
    gemm_kernel<<<(B_TOT / 128) * (1024 / 128), 256, 0, stream>>>(
        (const unsigned short*)A, (const unsigned short*)BT, C);
    epi_kernel<<<(B_TOT * 64) / 256, 256, 0, stream>>>(C, fcw, fcb, out);
  } else {
    qnn_kernel<<<(B_TOT * 64) / 256, 256, 0, stream>>>(x, rot, crx, fcw, fcb, out);
  }
}